// Round 17
// baseline (729.186 us; speedup 1.0000x reference)
//
#include <hip/hip_runtime.h>
#include <hip/hip_bf16.h>
#include <cstdint>
#include <cstddef>

// N=20000, E=100000, G=32, HID=64, HEADS=8, HC=64, HO=512, L=3, K=4. All fp32.
// Proven: projections at N-level (Mk=WqWk^T, Me=WqWe^T; Wv/We post-agg),
// flash-fused CSR attention (reg-resident edge list, depth-1 pipelined gathers),
// R9 tile-GEMM pattern everywhere.
// R17: R16's reg double-buffer in nf_gemm2 was SPILLED (VGPR capped at 68 by
// default launch_bounds; FETCH/WRITE +20MB scratch traffic). Fix: declare
// __launch_bounds__(256,3) (LDS caps at 3 blocks/CU anyway) so the 48 prefetch
// regs stay in the register file.

// ---------------- embed / init ----------------

__global__ void __launch_bounds__(256) k_node_embed(
    const float* __restrict__ x, const float* __restrict__ neW, const float* __restrict__ neb,
    float* __restrict__ h, int N)
{
    int idx = blockIdx.x * 256 + threadIdx.x;
    int n = idx >> 6, c = idx & 63;
    if (n >= N) return;
    float acc = neb[c];
    #pragma unroll
    for (int j = 0; j < 7; ++j) acc += x[(size_t)n * 7 + j] * neW[j * 64 + c];
    h[(size_t)n * 64 + c] = fmaxf(acc, 0.f);
}

__global__ void __launch_bounds__(256) k_edge_w(
    const float* __restrict__ x,
    const float* __restrict__ means, const float* __restrict__ log_stds,
    const int* __restrict__ src, const int* __restrict__ dst,
    float* __restrict__ wbuf, int E)
{
    int e = blockIdx.x * 256 + threadIdx.x;
    if (e >= E) return;
    int s = src[e], d = dst[e];
    const float* ps = x + (size_t)s * 7;
    const float* pd = x + (size_t)d * 7;
    float slx = ps[0], sly = ps[1], srx = ps[2], sry = ps[3];
    float dlx = pd[0], dly = pd[1], drx = pd[2], dry = pd[3];
    float u[8];
    float rx, ry;
    rx = dlx - slx; ry = dly - sly; u[0] = sqrtf(rx*rx + ry*ry); u[1] = atan2f(ry, rx);
    rx = dlx - srx; ry = dly - sry; u[2] = sqrtf(rx*rx + ry*ry); u[3] = atan2f(ry, rx);
    rx = drx - slx; ry = dry - sly; u[4] = sqrtf(rx*rx + ry*ry); u[5] = atan2f(ry, rx);
    rx = drx - srx; ry = dry - sry; u[6] = sqrtf(rx*rx + ry*ry); u[7] = atan2f(ry, rx);
    #pragma unroll
    for (int kk = 0; kk < 4; ++kk) {
        float ssum = 0.f;
        #pragma unroll
        for (int dd = 0; dd < 8; ++dd) {
            float stdv = expf(log_stds[kk*8+dd]) + 1e-6f;
            float z = (u[dd] - means[kk*8+dd]) / stdv;
            ssum += z * z;
        }
        wbuf[(size_t)e*4 + kk] = expf(-0.5f * ssum);
    }
}

__global__ void __launch_bounds__(256) k_edge_ea(
    const float* __restrict__ edge_attr, const float* __restrict__ wbuf,
    const float* __restrict__ spW, const float* __restrict__ spb,
    const float* __restrict__ eeW, const float* __restrict__ eeb,
    float* __restrict__ ea, int E)
{
    int idx = blockIdx.x * 256 + threadIdx.x;
    int e = idx >> 6, c = idx & 63;
    if (e >= E) return;
    float acce = eeb[c];
    #pragma unroll
    for (int j = 0; j < 4; ++j) acce += edge_attr[(size_t)e*4 + j] * eeW[j*64 + c];
    float accs = spb[c];
    #pragma unroll
    for (int j = 0; j < 4; ++j) accs += wbuf[(size_t)e*4 + j] * spW[j*64 + c];
    ea[(size_t)e*64 + c] = fmaxf(acce, 0.f) + fmaxf(accs, 0.f);
}

// ---------------- CSR build ----------------

__global__ void __launch_bounds__(256) k_hist(
    const int* __restrict__ dst, int* __restrict__ deg, int E)
{
    int e = blockIdx.x * 256 + threadIdx.x;
    if (e < E) atomicAdd(deg + dst[e], 1);
}

__global__ void __launch_bounds__(1024) k_scan(
    const int* __restrict__ deg, int* __restrict__ ptr, int* __restrict__ headw, int N)
{
    __shared__ int part[1024];
    int t = threadIdx.x;
    int per = (N + 1023) / 1024;
    int s = 0;
    for (int i = 0; i < per; ++i) { int idx = t*per + i; if (idx < N) s += deg[idx]; }
    part[t] = s;
    __syncthreads();
    for (int off = 1; off < 1024; off <<= 1) {
        int v = (t >= off) ? part[t - off] : 0;
        __syncthreads();
        part[t] += v;
        __syncthreads();
    }
    int base = (t > 0) ? part[t - 1] : 0;
    for (int i = 0; i < per; ++i) {
        int idx = t*per + i;
        if (idx < N) { ptr[idx] = base; headw[idx] = base; base += deg[idx]; }
    }
    if (t == 1023) ptr[N] = part[1023];
}

__global__ void __launch_bounds__(256) k_scatter(
    const int* __restrict__ dst, const int* __restrict__ src, const int* __restrict__ batch,
    int* __restrict__ headw, int2* __restrict__ ipair, int* __restrict__ ieb, int E)
{
    int e = blockIdx.x * 256 + threadIdx.x;
    if (e < E) {
        int s = src[e];
        int pos = atomicAdd(headw + dst[e], 1);
        ipair[pos] = make_int2(s, e);
        ieb[e] = batch[s];
    }
}

// ---------------- weight precompute (all layers, hoisted) ----------------

__global__ void __launch_bounds__(256) k_wprod_all(
    const float* __restrict__ Wq, const float* __restrict__ bq,
    const float* __restrict__ Wk, const float* __restrict__ We,
    float* __restrict__ Mk, float* __restrict__ Me,
    float* __restrict__ bqk, float* __restrict__ bqe)
{
    int h = blockIdx.x;
    int which = blockIdx.y;
    int l = blockIdx.z;
    const float* Wq_l = Wq + (size_t)l * 64 * 512;
    const float* bq_l = bq + (size_t)l * 512;
    const float* Wx_l = (which ? We : Wk) + (size_t)l * 64 * 512;
    float* M  = (which ? Me : Mk) + (size_t)l * 64 * 512;
    float* bM = (which ? bqe : bqk) + (size_t)l * 512;
    __shared__ float wq_s[65][64];
    __shared__ float wx_s[64][65];
    int tid = threadIdx.x;
    for (int i = tid; i < 4096; i += 256) {
        int r = i >> 6, c2 = i & 63;
        wq_s[r][c2] = Wq_l[(size_t)r*512 + h*64 + c2];
        wx_s[r][c2] = Wx_l[(size_t)r*512 + h*64 + c2];
    }
    if (tid < 64) wq_s[64][tid] = bq_l[h*64 + tid];
    __syncthreads();
    int j = tid & 63, cg = tid >> 6;
    for (int c = cg*16; c < cg*16 + 16; ++c) {
        float s = 0.f;
        #pragma unroll 8
        for (int c2 = 0; c2 < 64; ++c2) s += wq_s[c][c2] * wx_s[j][c2];
        M[(size_t)c*512 + h*64 + j] = s;
    }
    if (tid < 64) {
        float s = 0.f;
        #pragma unroll 8
        for (int c2 = 0; c2 < 64; ++c2) s += wq_s[64][c2] * wx_s[tid][c2];
        bM[h*64 + tid] = s;
    }
}

__global__ void __launch_bounds__(64) k_wqb_all(
    const float* __restrict__ Wq, const float* __restrict__ bq,
    const float* __restrict__ bk, const float* __restrict__ be,
    float* __restrict__ wqb, float* __restrict__ cb)
{
    int l = blockIdx.x;
    const float* Wq_l = Wq + (size_t)l * 64 * 512;
    const float* bq_l = bq + (size_t)l * 512;
    const float* bk_l = bk + (size_t)l * 512;
    const float* be_l = be + (size_t)l * 512;
    float* wqb_l = wqb + (size_t)l * 512;
    float* cb_l  = cb + (size_t)l * 8;
    int c = threadIdx.x;
    for (int h = 0; h < 8; ++h) {
        float s = 0.f;
        for (int c2 = 0; c2 < 64; ++c2)
            s += Wq_l[(size_t)c*512 + h*64 + c2] * (bk_l[h*64+c2] + be_l[h*64+c2]);
        wqb_l[c*8 + h] = s;
    }
    if (c < 8) {
        float s = 0.f;
        for (int c2 = 0; c2 < 64; ++c2)
            s += bq_l[c*64 + c2] * (bk_l[c*64+c2] + be_l[c*64+c2]);
        cb_l[c] = s;
    }
}

// ---------------- projection GEMM (R9 pattern, 16 y-blocks) ----------------

__global__ void __launch_bounds__(256) k_proj16(
    const float* __restrict__ h,
    const float* __restrict__ Mk, const float* __restrict__ bqk, float* __restrict__ qk,
    const float* __restrict__ Me, const float* __restrict__ bqe, float* __restrict__ qe2,
    int N)
{
    __shared__ float As[64][132];
    __shared__ __align__(16) float Wt[64][64];
    int tid = threadIdx.x;
    int y = blockIdx.y;
    int which = y >> 3, yb = y & 7;
    const float* W    = which ? Me : Mk;
    const float* bias = (which ? bqe : bqk) + yb * 64;
    float* Y          = which ? qe2 : qk;
    int n0 = blockIdx.x * 128;
    {
        int rt = tid & 127;
        int n = n0 + rt;
        int jh = (tid >> 7) * 32;
        if (n < N) {
            const float* ap = h + (size_t)n*64;
            #pragma unroll
            for (int j4 = 0; j4 < 8; ++j4) {
                int j = jh + j4 * 4;
                float4 a = *(const float4*)(ap + j);
                As[j+0][rt] = a.x; As[j+1][rt] = a.y;
                As[j+2][rt] = a.z; As[j+3][rt] = a.w;
            }
        } else {
            #pragma unroll
            for (int j4 = 0; j4 < 8; ++j4) {
                int j = jh + j4 * 4;
                As[j+0][rt] = 0.f; As[j+1][rt] = 0.f;
                As[j+2][rt] = 0.f; As[j+3][rt] = 0.f;
            }
        }
        #pragma unroll
        for (int i = 0; i < 4; ++i) {
            int idx = tid + i * 256;
            int j = idx >> 4, c4 = (idx & 15) * 4;
            *(float4*)&Wt[j][c4] = *(const float4*)(W + (size_t)j*512 + yb*64 + c4);
        }
    }
    __syncthreads();
    int wv = tid >> 6, lane = tid & 63;
    int rg = lane >> 3, cg = lane & 7;
    int c0 = cg * 8;
    int rbase = wv * 32 + rg * 4;
    float acc[4][8];
    float4 b0 = *(const float4*)(bias + c0);
    float4 b1 = *(const float4*)(bias + c0 + 4);
    #pragma unroll
    for (int t = 0; t < 4; ++t) {
        acc[t][0]=b0.x; acc[t][1]=b0.y; acc[t][2]=b0.z; acc[t][3]=b0.w;
        acc[t][4]=b1.x; acc[t][5]=b1.y; acc[t][6]=b1.z; acc[t][7]=b1.w;
    }
    #pragma unroll 4
    for (int j = 0; j < 64; ++j) {
        float4 av = *(const float4*)&As[j][rbase];
        float4 w0 = *(const float4*)&Wt[j][c0];
        float4 w1 = *(const float4*)&Wt[j][c0 + 4];
        acc[0][0] += av.x*w0.x; acc[0][1] += av.x*w0.y; acc[0][2] += av.x*w0.z; acc[0][3] += av.x*w0.w;
        acc[0][4] += av.x*w1.x; acc[0][5] += av.x*w1.y; acc[0][6] += av.x*w1.z; acc[0][7] += av.x*w1.w;
        acc[1][0] += av.y*w0.x; acc[1][1] += av.y*w0.y; acc[1][2] += av.y*w0.z; acc[1][3] += av.y*w0.w;
        acc[1][4] += av.y*w1.x; acc[1][5] += av.y*w1.y; acc[1][6] += av.y*w1.z; acc[1][7] += av.y*w1.w;
        acc[2][0] += av.z*w0.x; acc[2][1] += av.z*w0.y; acc[2][2] += av.z*w0.z; acc[2][3] += av.z*w0.w;
        acc[2][4] += av.z*w1.x; acc[2][5] += av.z*w1.y; acc[2][6] += av.z*w1.z; acc[2][7] += av.z*w1.w;
        acc[3][0] += av.w*w0.x; acc[3][1] += av.w*w0.y; acc[3][2] += av.w*w0.z; acc[3][3] += av.w*w0.w;
        acc[3][4] += av.w*w1.x; acc[3][5] += av.w*w1.y; acc[3][6] += av.w*w1.z; acc[3][7] += av.w*w1.w;
    }
    #pragma unroll
    for (int t = 0; t < 4; ++t) {
        int n = n0 + rbase + t;
        if (n < N) {
            float4 o0 = {acc[t][0],acc[t][1],acc[t][2],acc[t][3]};
            float4 o1 = {acc[t][4],acc[t][5],acc[t][6],acc[t][7]};
            *(float4*)(Y + (size_t)n*512 + yb*64 + c0)     = o0;
            *(float4*)(Y + (size_t)n*512 + yb*64 + c0 + 4) = o1;
        }
    }
}

// ---------------- fused CSR attention (flash-style, reg-resident edge list) ----------------

__global__ void __launch_bounds__(256) k_attn_fused(
    const float* __restrict__ qk, const float* __restrict__ qe2,
    const float* __restrict__ wqb, const float* __restrict__ cb,
    const float* __restrict__ ea, const float* __restrict__ hbuf,
    const int* __restrict__ ptr, const int2* __restrict__ ipair,
    float* __restrict__ hagg, float* __restrict__ tbuf, float* __restrict__ sbuf, int N)
{
    int wv = threadIdx.x >> 6, lane = threadIdx.x & 63;
    int n = blockIdx.x * 4 + wv;
    if (n >= N) return;
    int h = lane >> 3, p = lane & 7;
    int b = ptr[n], e_ = ptr[n + 1];
    int deg = e_ - b;
    const float4* xp = (const float4*)(qk + (size_t)n*512 + lane*8);
    float4 x0 = xp[0], x1 = xp[1];
    const float4* gp = (const float4*)(qe2 + (size_t)n*512 + lane*8);
    float4 g0 = gp[0], g1 = gp[1];
    const float4* hdp = (const float4*)(hbuf + (size_t)n*64 + p*8);
    float4 hd0 = hdp[0], hd1 = hdp[1];
    float qbh = hd0.x*wqb[(p*8+0)*8+h] + hd0.y*wqb[(p*8+1)*8+h]
              + hd0.z*wqb[(p*8+2)*8+h] + hd0.w*wqb[(p*8+3)*8+h]
              + hd1.x*wqb[(p*8+4)*8+h] + hd1.y*wqb[(p*8+5)*8+h]
              + hd1.z*wqb[(p*8+6)*8+h] + hd1.w*wqb[(p*8+7)*8+h];
    qbh += __shfl_xor(qbh, 1);
    qbh += __shfl_xor(qbh, 2);
    qbh += __shfl_xor(qbh, 4);
    qbh += cb[h];
    float m = -3.4e38f, den = 0.f;
    float hacc[8], tacc[8];
    #pragma unroll
    for (int i = 0; i < 8; ++i) { hacc[i] = 0.f; tacc[i] = 0.f; }
    for (int base = 0; base < deg; base += 64) {
        int cnt = deg - base; if (cnt > 64) cnt = 64;
        int2 myp = (lane < cnt) ? ipair[b + base + lane] : make_int2(0, 0);
        int s0i = __shfl(myp.x, 0), e0i = __shfl(myp.y, 0);
        const float4* hp = (const float4*)(hbuf + (size_t)s0i*64 + p*8);
        const float4* ap = (const float4*)(ea + (size_t)e0i*64 + p*8);
        float4 h0 = hp[0], h1 = hp[1];
        float4 a0 = ap[0], a1 = ap[1];
        for (int i = 0; i < cnt; ++i) {
            float4 h0c = h0, h1c = h1, a0c = a0, a1c = a1;
            if (i + 1 < cnt) {
                int sn = __shfl(myp.x, i + 1), en = __shfl(myp.y, i + 1);
                const float4* hpn = (const float4*)(hbuf + (size_t)sn*64 + p*8);
                const float4* apn = (const float4*)(ea + (size_t)en*64 + p*8);
                h0 = hpn[0]; h1 = hpn[1]; a0 = apn[0]; a1 = apn[1];
            }
            float t = x0.x*h0c.x + x0.y*h0c.y + x0.z*h0c.z + x0.w*h0c.w
                    + x1.x*h1c.x + x1.y*h1c.y + x1.z*h1c.z + x1.w*h1c.w
                    + g0.x*a0c.x + g0.y*a0c.y + g0.z*a0c.z + g0.w*a0c.w
                    + g1.x*a1c.x + g1.y*a1c.y + g1.z*a1c.z + g1.w*a1c.w;
            t += __shfl_xor(t, 1);
            t += __shfl_xor(t, 2);
            t += __shfl_xor(t, 4);
            float al = 0.125f * (t + qbh);
            float mn = fmaxf(m, al);
            float r = expf(m - mn);
            float w = expf(al - mn);
            den = den * r + w;
            m = mn;
            hacc[0] = hacc[0]*r + w*h0c.x; hacc[1] = hacc[1]*r + w*h0c.y;
            hacc[2] = hacc[2]*r + w*h0c.z; hacc[3] = hacc[3]*r + w*h0c.w;
            hacc[4] = hacc[4]*r + w*h1c.x; hacc[5] = hacc[5]*r + w*h1c.y;
            hacc[6] = hacc[6]*r + w*h1c.z; hacc[7] = hacc[7]*r + w*h1c.w;
            tacc[0] = tacc[0]*r + w*a0c.x; tacc[1] = tacc[1]*r + w*a0c.y;
            tacc[2] = tacc[2]*r + w*a0c.z; tacc[3] = tacc[3]*r + w*a0c.w;
            tacc[4] = tacc[4]*r + w*a1c.x; tacc[5] = tacc[5]*r + w*a1c.y;
            tacc[6] = tacc[6]*r + w*a1c.z; tacc[7] = tacc[7]*r + w*a1c.w;
        }
    }
    float inv = 0.125f / (den + 1e-16f);
    float4 o;
    o = {hacc[0]*inv,hacc[1]*inv,hacc[2]*inv,hacc[3]*inv};
    *(float4*)(hagg + (size_t)n*512 + lane*8)     = o;
    o = {hacc[4]*inv,hacc[5]*inv,hacc[6]*inv,hacc[7]*inv};
    *(float4*)(hagg + (size_t)n*512 + lane*8 + 4) = o;
    o = {tacc[0]*inv,tacc[1]*inv,tacc[2]*inv,tacc[3]*inv};
    *(float4*)(tbuf + (size_t)n*512 + lane*8)     = o;
    o = {tacc[4]*inv,tacc[5]*inv,tacc[6]*inv,tacc[7]*inv};
    *(float4*)(tbuf + (size_t)n*512 + lane*8 + 4) = o;
    if (p == 0) sbuf[(size_t)n*8 + h] = den * inv;
}

// Paired partial GEMM, grid (ceil(N/128), 8): round0 = tbuf_y@We_y (direct LDS
// stage), round1 = hagg_y@Wv_y (register-prefetched during round0).
// __launch_bounds__(256,3): LDS caps at 3 blocks/CU; allow ~168 VGPRs so the
// prefetch arrays stay in registers (R16: spilled at the default 68-reg cap).
__global__ void __launch_bounds__(256, 3) k_nf_gemm2(
    const float* __restrict__ tbuf, const float* __restrict__ hagg,
    const float* __restrict__ We, const float* __restrict__ Wv,
    float* __restrict__ pbuf, int N)
{
    __shared__ float As[64][132];
    __shared__ __align__(16) float Wt[64][64];
    int tid = threadIdx.x;
    int y = blockIdx.y;
    int n0 = blockIdx.x * 128;
    int rt = tid & 127;
    int jh = (tid >> 7) * 32;
    int nrow = n0 + rt;
    bool rowok = (nrow < N);
    // ---- stage round 0 (tbuf, We) directly into LDS ----
    {
        if (rowok) {
            const float* ap = tbuf + (size_t)nrow*512 + y*64;
            #pragma unroll
            for (int j4 = 0; j4 < 8; ++j4) {
                int j = jh + j4 * 4;
                float4 a = *(const float4*)(ap + j);
                As[j+0][rt] = a.x; As[j+1][rt] = a.y;
                As[j+2][rt] = a.z; As[j+3][rt] = a.w;
            }
        } else {
            #pragma unroll
            for (int j4 = 0; j4 < 8; ++j4) {
                int j = jh + j4 * 4;
                As[j+0][rt] = 0.f; As[j+1][rt] = 0.f;
                As[j+2][rt] = 0.f; As[j+3][rt] = 0.f;
            }
        }
        #pragma unroll
        for (int i = 0; i < 4; ++i) {
            int idx = tid + i * 256;
            int j = idx >> 4, c4 = (idx & 15) * 4;
            *(float4*)&Wt[j][c4] = *(const float4*)(We + (size_t)j*512 + y*64 + c4);
        }
    }
    __syncthreads();
    // ---- prefetch round 1 (hagg, Wv) into registers ----
    float4 pa[8];
    float4 pw[4];
    if (rowok) {
        const float* ap2 = hagg + (size_t)nrow*512 + y*64;
        #pragma unroll
        for (int j4 = 0; j4 < 8; ++j4) pa[j4] = *(const float4*)(ap2 + jh + j4*4);
    } else {
        #pragma unroll
        for (int j4 = 0; j4 < 8; ++j4) pa[j4] = make_float4(0.f, 0.f, 0.f, 0.f);
    }
    #pragma unroll
    for (int i = 0; i < 4; ++i) {
        int idx = tid + i * 256;
        int j = idx >> 4, c4 = (idx & 15) * 4;
        pw[i] = *(const float4*)(Wv + (size_t)j*512 + y*64 + c4);
    }
    int wv = tid >> 6, lane = tid & 63;
    int rg = lane >> 3, cg = lane & 7;
    int c0 = cg * 8;
    int rbase = wv * 32 + rg * 4;
    float acc[4][8];
    #pragma unroll
    for (int t = 0; t < 4; ++t)
        #pragma unroll
        for (int i = 0; i < 8; ++i) acc[t][i] = 0.f;
    // ---- compute round 0 ----
    #pragma unroll 4
    for (int j = 0; j < 64; ++j) {
        float4 av = *(const float4*)&As[j][rbase];
        float4 w0 = *(const float4*)&Wt[j][c0];
        float4 w1 = *(const float4*)&Wt[j][c0 + 4];
        acc[0][0] += av.x*w0.x; acc[0][1] += av.x*w0.y; acc[0][2] += av.x*w0.z; acc[0][3] += av.x*w0.w;
        acc[0][4] += av.x*w1.x; acc[0][5] += av.x*w1.y; acc[0][6] += av.x*w1.z; acc[0][7] += av.x*w1.w;
        acc[1][0] += av.y*w0.x; acc[1][1] += av.y*w0.y; acc[1][2] += av.y*w0.z; acc[1][3] += av.y*w0.w;
        acc[1][4] += av.y*w1.x; acc[1][5] += av.y*w1.y; acc[1][6] += av.y*w1.z; acc[1][7] += av.y*w1.w;
        acc[2][0] += av.z*w0.x; acc[2][1] += av.z*w0.y; acc[2][2] += av.z*w0.z; acc[2][3] += av.z*w0.w;
        acc[2][4] += av.z*w1.x; acc[2][5] += av.z*w1.y; acc[2][6] += av.z*w1.z; acc[2][7] += av.z*w1.w;
        acc[3][0] += av.w*w0.x; acc[3][1] += av.w*w0.y; acc[3][2] += av.w*w0.z; acc[3][3] += av.w*w0.w;
        acc[3][4] += av.w*w1.x; acc[3][5] += av.w*w1.y; acc[3][6] += av.w*w1.z; acc[3][7] += av.w*w1.w;
    }
    __syncthreads();
    // ---- dump round-1 regs to LDS ----
    #pragma unroll
    for (int j4 = 0; j4 < 8; ++j4) {
        int j = jh + j4 * 4;
        As[j+0][rt] = pa[j4].x; As[j+1][rt] = pa[j4].y;
        As[j+2][rt] = pa[j4].z; As[j+3][rt] = pa[j4].w;
    }
    #pragma unroll
    for (int i = 0; i < 4; ++i) {
        int idx = tid + i * 256;
        int j = idx >> 4, c4 = (idx & 15) * 4;
        *(float4*)&Wt[j][c4] = pw[i];
    }
    __syncthreads();
    // ---- compute round 1 ----
    #pragma unroll 4
    for (int j = 0; j < 64; ++j) {
        float4 av = *(const float4*)&As[j][rbase];
        float4 w0 = *(const float4*)&Wt[j][c0];
        float4 w1 = *(const float4*)&Wt[j][c0 + 4];
        acc[0][0] += av.x*w0.x; acc[0][1] += av.x*w0.y; acc[0][2] += av.x*w0.z; acc[0][3] += av.x*w0.w;
        acc[0][4] += av.x*w1.x; acc[0][5] += av.x*w1.y; acc[0][6] += av.x*w1.z; acc[0][7] += av.x*w1.w;
        acc[1][0] += av.y*w0.x; acc[1][1] += av.y*w0.y; acc[1][2] += av.y*w0.z; acc[1][3] += av.y*w0.w;
        acc[1][4] += av.y*w1.x; acc[1][5] += av.y*w1.y; acc[1][6] += av.y*w1.z; acc[1][7] += av.y*w1.w;
        acc[2][0] += av.z*w0.x; acc[2][1] += av.z*w0.y; acc[2][2] += av.z*w0.z; acc[2][3] += av.z*w0.w;
        acc[2][4] += av.z*w1.x; acc[2][5] += av.z*w1.y; acc[2][6] += av.z*w1.z; acc[2][7] += av.z*w1.w;
        acc[3][0] += av.w*w0.x; acc[3][1] += av.w*w0.y; acc[3][2] += av.w*w0.z; acc[3][3] += av.w*w0.w;
        acc[3][4] += av.w*w1.x; acc[3][5] += av.w*w1.y; acc[3][6] += av.w*w1.z; acc[3][7] += av.w*w1.w;
    }
    float* out = pbuf + (size_t)y * N * 64;
    #pragma unroll
    for (int t = 0; t < 4; ++t) {
        int n = n0 + rbase + t;
        if (n < N) {
            float4 o0 = {acc[t][0],acc[t][1],acc[t][2],acc[t][3]};
            float4 o1 = {acc[t][4],acc[t][5],acc[t][6],acc[t][7]};
            *(float4*)(out + (size_t)n*64 + c0)     = o0;
            *(float4*)(out + (size_t)n*64 + c0 + 4) = o1;
        }
    }
}

__global__ void __launch_bounds__(256) k_nf_reduce2(
    const float* __restrict__ pbuf, const float* __restrict__ hin,
    const float* __restrict__ sbuf, const float* __restrict__ Ws,
    const float* __restrict__ be, const float* __restrict__ bv,
    const float* __restrict__ bs, float* __restrict__ hnext, int N)
{
    int idx = blockIdx.x * 256 + threadIdx.x;
    int n = idx >> 6, cc = idx & 63;
    if (n >= N) return;
    float a = bs[cc];
    #pragma unroll
    for (int y = 0; y < 8; ++y) a += pbuf[(size_t)y*N*64 + (size_t)n*64 + cc];
    float hv = hin[(size_t)n*64 + cc];
    #pragma unroll 8
    for (int j = 0; j < 64; ++j) a += __shfl(hv, j) * Ws[(size_t)j*64 + cc];
    #pragma unroll
    for (int h = 0; h < 8; ++h)
        a += sbuf[(size_t)n*8 + h] * (be[h*64 + cc] + bv[h*64 + cc]);
    hnext[(size_t)n*64 + cc] = fmaxf(a, 0.f);
}

// hw[n][y*64+cc] = Σ_j h[n][j] euW[y*4096 + j*64 + cc]   grid (ceil(N/128), 2)
__global__ void __launch_bounds__(256) k_eu_pre(
    const float* __restrict__ h, const float* __restrict__ euW,
    float* __restrict__ hw, int N)
{
    __shared__ float As[64][132];
    __shared__ __align__(16) float Wt[64][64];
    int tid = threadIdx.x;
    int y = blockIdx.y;
    int n0 = blockIdx.x * 128;
    {
        int rt = tid & 127;
        int n = n0 + rt;
        int jh = (tid >> 7) * 32;
        if (n < N) {
            const float* ap = h + (size_t)n*64;
            #pragma unroll
            for (int j4 = 0; j4 < 8; ++j4) {
                int j = jh + j4 * 4;
                float4 a = *(const float4*)(ap + j);
                As[j+0][rt] = a.x; As[j+1][rt] = a.y;
                As[j+2][rt] = a.z; As[j+3][rt] = a.w;
            }
        } else {
            #pragma unroll
            for (int j4 = 0; j4 < 8; ++j4) {
                int j = jh + j4 * 4;
                As[j+0][rt] = 0.f; As[j+1][rt] = 0.f;
                As[j+2][rt] = 0.f; As[j+3][rt] = 0.f;
            }
        }
        #pragma unroll
        for (int i = 0; i < 4; ++i) {
            int idx = tid + i * 256;
            *(float4*)&Wt[idx >> 4][(idx & 15) * 4] =
                *(const float4*)(euW + (size_t)y*4096 + idx * 4);
        }
    }
    __syncthreads();
    int wv = tid >> 6, lane = tid & 63;
    int rg = lane >> 3, cg = lane & 7;
    int c0 = cg * 8;
    int rbase = wv * 32 + rg * 4;
    float acc[4][8];
    #pragma unroll
    for (int t = 0; t < 4; ++t)
        #pragma unroll
        for (int i = 0; i < 8; ++i) acc[t][i] = 0.f;
    #pragma unroll 4
    for (int j = 0; j < 64; ++j) {
        float4 av = *(const float4*)&As[j][rbase];
        float4 w0 = *(const float4*)&Wt[j][c0];
        float4 w1 = *(const float4*)&Wt[j][c0 + 4];
        acc[0][0] += av.x*w0.x; acc[0][1] += av.x*w0.y; acc[0][2] += av.x*w0.z; acc[0][3] += av.x*w0.w;
        acc[0][4] += av.x*w1.x; acc[0][5] += av.x*w1.y; acc[0][6] += av.x*w1.z; acc[0][7] += av.x*w1.w;
        acc[1][0] += av.y*w0.x; acc[1][1] += av.y*w0.y; acc[1][2] += av.y*w0.z; acc[1][3] += av.y*w0.w;
        acc[1][4] += av.y*w1.x; acc[1][5] += av.y*w1.y; acc[1][6] += av.y*w1.z; acc[1][7] += av.y*w1.w;
        acc[2][0] += av.z*w0.x; acc[2][1] += av.z*w0.y; acc[2][2] += av.z*w0.z; acc[2][3] += av.z*w0.w;
        acc[2][4] += av.z*w1.x; acc[2][5] += av.z*w1.y; acc[2][6] += av.z*w1.z; acc[2][7] += av.z*w1.w;
        acc[3][0] += av.w*w0.x; acc[3][1] += av.w*w0.y; acc[3][2] += av.w*w0.z; acc[3][3] += av.w*w0.w;
        acc[3][4] += av.w*w1.x; acc[3][5] += av.w*w1.y; acc[3][6] += av.w*w1.z; acc[3][7] += av.w*w1.w;
    }
    #pragma unroll
    for (int t = 0; t < 4; ++t) {
        int n = n0 + rbase + t;
        if (n < N) {
            float4 o0 = {acc[t][0],acc[t][1],acc[t][2],acc[t][3]};
            float4 o1 = {acc[t][4],acc[t][5],acc[t][6],acc[t][7]};
            *(float4*)(hw + (size_t)n*128 + y*64 + c0)     = o0;
            *(float4*)(hw + (size_t)n*128 + y*64 + c0 + 4) = o1;
        }
    }
}

// ea2 = relu( hw[src][0:64] + hw[dst][64:128] + ea@W3 + eub )
__global__ void __launch_bounds__(256) k_edge_update2(
    const float* __restrict__ hw, const float* __restrict__ ea,
    const float* __restrict__ euW2, const float* __restrict__ eub,
    const int* __restrict__ src, const int* __restrict__ dst,
    float* __restrict__ ea2, int E)
{
    __shared__ float As[64][132];
    __shared__ __align__(16) float Wt[64][64];
    __shared__ int sid[128], did[128];
    int tid = threadIdx.x;
    int e0 = blockIdx.x * 128;
    if (tid < 128) {
        int e = e0 + tid; if (e >= E) e = E - 1;
        sid[tid] = src[e]; did[tid] = dst[e];
    }
    {
        int et = tid & 127;
        int e = e0 + et; if (e >= E) e = E - 1;
        const float* ap = ea + (size_t)e * 64;
        int jh = (tid >> 7) * 32;
        #pragma unroll
        for (int j4 = 0; j4 < 8; ++j4) {
            int j = jh + j4 * 4;
            float4 a = *(const float4*)(ap + j);
            As[j+0][et] = a.x; As[j+1][et] = a.y;
            As[j+2][et] = a.z; As[j+3][et] = a.w;
        }
        #pragma unroll
        for (int i = 0; i < 4; ++i) {
            int idx = tid + i * 256;
            *(float4*)&Wt[idx >> 4][(idx & 15) * 4] = *(const float4*)(euW2 + idx * 4);
        }
    }
    __syncthreads();
    int wv = tid >> 6, lane = tid & 63;
    int rg = lane >> 3, cg = lane & 7;
    int c0 = cg * 8;
    int rbase = wv * 32 + rg * 4;
    float acc[4][8];
    float4 b0 = *(const float4*)(eub + c0);
    float4 b1 = *(const float4*)(eub + c0 + 4);
    #pragma unroll
    for (int t = 0; t < 4; ++t) {
        acc[t][0]=b0.x; acc[t][1]=b0.y; acc[t][2]=b0.z; acc[t][3]=b0.w;
        acc[t][4]=b1.x; acc[t][5]=b1.y; acc[t][6]=b1.z; acc[t][7]=b1.w;
    }
    #pragma unroll 4
    for (int j = 0; j < 64; ++j) {
        float4 av = *(const float4*)&As[j][rbase];
        float4 w0 = *(const float4*)&Wt[j][c0];
        float4 w1 = *(const float4*)&Wt[j][c0 + 4];
        acc[0][0] += av.x*w0.x; acc[0][1] += av.x*w0.y; acc[0][2] += av.x*w0.z; acc[0][3] += av.x*w0.w;
        acc[0][4] += av.x*w1.x; acc[0][5] += av.x*w1.y; acc[0][6] += av.x*w1.z; acc[0][7] += av.x*w1.w;
        acc[1][0] += av.y*w0.x; acc[1][1] += av.y*w0.y; acc[1][2] += av.y*w0.z; acc[1][3] += av.y*w0.w;
        acc[1][4] += av.y*w1.x; acc[1][5] += av.y*w1.y; acc[1][6] += av.y*w1.z; acc[1][7] += av.y*w1.w;
        acc[2][0] += av.z*w0.x; acc[2][1] += av.z*w0.y; acc[2][2] += av.z*w0.z; acc[2][3] += av.z*w0.w;
        acc[2][4] += av.z*w1.x; acc[2][5] += av.z*w1.y; acc[2][6] += av.z*w1.z; acc[2][7] += av.z*w1.w;
        acc[3][0] += av.w*w0.x; acc[3][1] += av.w*w0.y; acc[3][2] += av.w*w0.z; acc[3][3] += av.w*w0.w;
        acc[3][4] += av.w*w1.x; acc[3][5] += av.w*w1.y; acc[3][6] += av.w*w1.z; acc[3][7] += av.w*w1.w;
    }
    #pragma unroll
    for (int t = 0; t < 4; ++t) {
        int e = e0 + rbase + t;
        if (e < E) {
            int s = sid[rbase + t], d = did[rbase + t];
            const float4* sp = (const float4*)(hw + (size_t)s*128 + c0);
            const float4* dp = (const float4*)(hw + (size_t)d*128 + 64 + c0);
            float4 s0 = sp[0], s1 = sp[1];
            float4 d0 = dp[0], d1 = dp[1];
            float4 o0 = {fmaxf(acc[t][0]+s0.x+d0.x,0.f), fmaxf(acc[t][1]+s0.y+d0.y,0.f),
                         fmaxf(acc[t][2]+s0.z+d0.z,0.f), fmaxf(acc[t][3]+s0.w+d0.w,0.f)};
            float4 o1 = {fmaxf(acc[t][4]+s1.x+d1.x,0.f), fmaxf(acc[t][5]+s1.y+d1.y,0.f),
                         fmaxf(acc[t][6]+s1.z+d1.z,0.f), fmaxf(acc[t][7]+s1.w+d1.w,0.f)};
            *(float4*)(ea2 + (size_t)e*64 + c0)     = o0;
            *(float4*)(ea2 + (size_t)e*64 + c0 + 4) = o1;
        }
    }
}

// ---------------- pooling / head ----------------

__global__ void __launch_bounds__(64) k_node_pool(
    const float* __restrict__ h, const int* __restrict__ batch,
    float* __restrict__ npool, float* __restrict__ cn, int N)
{
    int lane = threadIdx.x;
    int n0 = blockIdx.x * 64;
    float acc = 0.f; int cur = -1; int run = 0;
    for (int i = 0; i < 64; ++i) {
        int n = n0 + i;
        if (n >= N) break;
        int b = batch[n];
        if (b != cur) {
            if (cur >= 0) {
                atomicAdd(npool + (size_t)cur*64 + lane, acc);
                if (lane == 0) atomicAdd(cn + cur, (float)run);
            }
            cur = b; acc = 0.f; run = 0;
        }
        acc += h[(size_t)n*64 + lane];
        ++run;
    }
    if (cur >= 0) {
        atomicAdd(npool + (size_t)cur*64 + lane, acc);
        if (lane == 0) atomicAdd(cn + cur, (float)run);
    }
}

__global__ void __launch_bounds__(256) k_edge_pool2(
    const float* __restrict__ ea, const int* __restrict__ ieb,
    float* __restrict__ rep, int E)
{
    __shared__ float pool_s[32][64];
    __shared__ float cnt_s[32];
    int tid = threadIdx.x;
    for (int i = tid; i < 2048; i += 256) ((float*)pool_s)[i] = 0.f;
    if (tid < 32) cnt_s[tid] = 0.f;
    __syncthreads();
    int wv = tid >> 6, lane = tid & 63;
    int base = blockIdx.x * 64 + wv * 16;
    int b16[16]; float v16[16];
    #pragma unroll
    for (int u = 0; u < 16; ++u) {
        int e = base + u;
        bool ok = (e < E);
        b16[u] = ok ? ieb[e] : -1;
        v16[u] = ok ? ea[(size_t)e*64 + lane] : 0.f;
    }
    #pragma unroll
    for (int u = 0; u < 16; ++u) {
        if (b16[u] >= 0) {
            atomicAdd(&pool_s[b16[u]][lane], v16[u]);
            if (lane == 0) atomicAdd(&cnt_s[b16[u]], 1.f);
        }
    }
    __syncthreads();
    float* myrep = rep + (size_t)(blockIdx.x & 7) * 2080;
    for (int i = tid; i < 2048; i += 256) atomicAdd(myrep + i, ((float*)pool_s)[i]);
    if (tid < 32) atomicAdd(myrep + 2048 + tid, cnt_s[tid]);
}

__global__ void __launch_bounds__(256) k_pool_merge(
    const float* __restrict__ rep, float* __restrict__ epool, float* __restrict__ ce)
{
    int i = blockIdx.x * 256 + threadIdx.x;
    if (i < 2080) {
        float s = 0.f;
        #pragma unroll
        for (int r = 0; r < 8; ++r) s += rep[(size_t)r*2080 + i];
        if (i < 2048) epool[i] = s; else ce[i - 2048] = s;
    }
}

__global__ void __launch_bounds__(64) k_head_mlp(
    const float* __restrict__ npool, const float* __restrict__ epool,
    const float* __restrict__ cn, const float* __restrict__ ce,
    const float* __restrict__ rW1, const float* __restrict__ rb1,
    const float* __restrict__ rW2, const float* __restrict__ rb2,
    const float* __restrict__ rW3, const float* __restrict__ rb3,
    float* __restrict__ out)
{
    __shared__ float g[128];
    __shared__ float h1[64];
    __shared__ float h2[64];
    int b = blockIdx.x, lane = threadIdx.x;
    float cnv = fmaxf(cn[b], 1.f), cev = fmaxf(ce[b], 1.f);
    g[lane]      = npool[(size_t)b*64 + lane] / cnv;
    g[64 + lane] = epool[(size_t)b*64 + lane] / cev;
    __syncthreads();
    float acc = rb1[lane];
    #pragma unroll 4
    for (int j = 0; j < 128; ++j) acc += g[j] * rW1[j*64 + lane];
    h1[lane] = fmaxf(acc, 0.f);
    __syncthreads();
    acc = rb2[lane];
    #pragma unroll 4
    for (int j = 0; j < 64; ++j) acc += h1[j] * rW2[j*64 + lane];
    h2[lane] = fmaxf(acc, 0.f);
    __syncthreads();
    if (lane < 2) {
        float o = rb3[lane];
        for (int j = 0; j < 64; ++j) o += h2[j] * rW3[j*2 + lane];
        out[b*2 + lane] = tanhf(o);
    }
}

// ---------------- launcher ----------------

extern "C" void kernel_launch(void* const* d_in, const int* in_sizes, int n_in,
                              void* d_out, int out_size, void* d_ws, size_t ws_size,
                              hipStream_t stream)
{
    const float* x         = (const float*)d_in[0];
    const float* edge_attr = (const float*)d_in[1];
    const float* means     = (const float*)d_in[2];
    const float* log_stds  = (const float*)d_in[3];
    const float* spW       = (const float*)d_in[4];
    const float* spb       = (const float*)d_in[5];
    const float* neW       = (const float*)d_in[6];
    const float* neb       = (const float*)d_in[7];
    const float* eeW       = (const float*)d_in[8];
    const float* eeb       = (const float*)d_in[9];
    const float* Wq        = (const float*)d_in[10];
    const float* bq        = (const float*)d_in[11];
    const float* Wk        = (const float*)d_in[12];
    const float* bk        = (const float*)d_in[13];
    const float* Wv        = (const float*)d_in[14];
    const float* bv        = (const float*)d_in[15];
    const float* We        = (const float*)d_in[16];
    const float* be        = (const float*)d_in[17];
    const float* Ws        = (const float*)d_in[18];
    const float* bs        = (const float*)d_in[19];
    const float* euW       = (const float*)d_in[20];
    const float* eub       = (const float*)d_in[21];
    const float* rW1       = (const float*)d_in[22];
    const float* rb1       = (const float*)d_in[23];
    const float* rW2       = (const float*)d_in[24];
    const float* rb2       = (const float*)d_in[25];
    const float* rW3       = (const float*)d_in[26];
    const float* rb3       = (const float*)d_in[27];
    const int* eidx        = (const int*)d_in[28];
    const int* batch       = (const int*)d_in[29];

    int N = in_sizes[0] / 7;
    int E = in_sizes[1] / 4;
    const int G = 32;
    const int* srcp = eidx;
    const int* dstp = eidx + E;

    float* ws = (float*)d_ws;
    size_t fl = 0;
    float* hA    = ws + fl; fl += (size_t)N * 64;
    float* hB    = ws + fl; fl += (size_t)N * 64;
    float* eaA   = ws + fl; fl += (size_t)E * 64;
    float* eaB   = ws + fl; fl += (size_t)E * 64;
    float* B1    = ws + fl; fl += (size_t)N * 512;   // qk -> hagg
    float* B2    = ws + fl; fl += (size_t)N * 512;   // qe2 -> tbuf
    float* B3    = ws + fl; fl += (size_t)N * 512;   // pbuf (8 x N64), then hw (N x 128)
    float* alpha = ws + fl; fl += (size_t)E * 8;     // wbuf (E*4) at init only
    float* sbuf  = ws + fl; fl += (size_t)N * 8;
    float* npool = ws + fl; fl += (size_t)G * 64;
    float* epool = ws + fl; fl += (size_t)G * 64;
    float* cn    = ws + fl; fl += G;
    float* ce    = ws + fl; fl += G;
    float* Mk3   = ws + fl; fl += 3 * 64 * 512;
    float* Me3   = ws + fl; fl += 3 * 64 * 512;
    float* bqk3  = ws + fl; fl += 3 * 512;
    float* bqe3  = ws + fl; fl += 3 * 512;
    float* wqb3  = ws + fl; fl += 3 * 512;
    float* cb3   = ws + fl; fl += 24;
    float* rep   = ws + fl; fl += 8 * 2080;
    int* ideg  = (int*)(ws + fl); fl += (size_t)N;
    int* ihead = (int*)(ws + fl); fl += (size_t)N;
    int2* ipair = (int2*)(ws + fl); fl += (size_t)E * 2;   // 8B-aligned (even offset)
    int* ieb   = (int*)(ws + fl); fl += (size_t)E;
    int* iptr  = (int*)(ws + fl); fl += (size_t)N + 1;
    // ~47.9M floats = 191.5 MB (ws known >= ~194 MB)

    float* wbuf = alpha;

    hipMemsetAsync(npool, 0, (size_t)(G * 130) * sizeof(float), stream);
    hipMemsetAsync(rep, 0, (size_t)(8 * 2080) * sizeof(float), stream);
    hipMemsetAsync(ideg, 0, (size_t)N * sizeof(int), stream);

    k_node_embed<<<(N * 64 + 255) / 256, 256, 0, stream>>>(x, neW, neb, hA, N);
    k_edge_w<<<(E + 255) / 256, 256, 0, stream>>>(x, means, log_stds, srcp, dstp, wbuf, E);
    k_edge_ea<<<((size_t)E * 64 + 255) / 256, 256, 0, stream>>>(edge_attr, wbuf,
                                                                spW, spb, eeW, eeb, eaA, E);
    k_hist<<<(E + 255) / 256, 256, 0, stream>>>(dstp, ideg, E);
    k_scan<<<1, 1024, 0, stream>>>(ideg, iptr, ihead, N);
    k_scatter<<<(E + 255) / 256, 256, 0, stream>>>(dstp, srcp, batch, ihead, ipair, ieb, E);
    k_wprod_all<<<dim3(8, 2, 3), 256, 0, stream>>>(Wq, bq, Wk, We, Mk3, Me3, bqk3, bqe3);
    k_wqb_all<<<3, 64, 0, stream>>>(Wq, bq, bk, be, wqb3, cb3);

    float* hcur = hA;  float* hnext = hB;
    float* eacur = eaA; float* eanext = eaB;
    for (int l = 0; l < 3; ++l) {
        const float* Wv_l = Wv + (size_t)l * 64 * 512;
        const float* We_l = We + (size_t)l * 64 * 512;
        const float* bv_l = bv + (size_t)l * 512;
        const float* be_l = be + (size_t)l * 512;
        const float* euW_l = euW + (size_t)l * 192 * 64;

        k_proj16<<<dim3((N + 127) / 128, 16), 256, 0, stream>>>(
            hcur,
            Mk3 + (size_t)l * 32768, bqk3 + (size_t)l * 512, B1,
            Me3 + (size_t)l * 32768, bqe3 + (size_t)l * 512, B2, N);

        k_attn_fused<<<(N + 3) / 4, 256, 0, stream>>>(B1, B2,
                                                      wqb3 + (size_t)l * 512,
                                                      cb3 + (size_t)l * 8,
                                                      eacur, hcur,
                                                      iptr, ipair,
                                                      B1 /*hagg*/, B2 /*tbuf*/, sbuf, N);
        k_nf_gemm2<<<dim3((N + 127) / 128, 8), 256, 0, stream>>>(B2, B1, We_l, Wv_l, B3, N);
        k_nf_reduce2<<<((size_t)N * 64 + 255) / 256, 256, 0, stream>>>(B3, hcur, sbuf,
                                                                       Ws + (size_t)l * 64 * 64,
                                                                       be_l, bv_l,
                                                                       bs + (size_t)l * 64,
                                                                       hnext, N);
        k_eu_pre<<<dim3((N + 127) / 128, 2), 256, 0, stream>>>(hnext, euW_l, B3, N);
        k_edge_update2<<<(E + 127) / 128, 256, 0, stream>>>(B3, eacur, euW_l + 2 * 4096,
                                                            eub + (size_t)l * 64,
                                                            srcp, dstp, eanext, E);
        float* t1 = hcur; hcur = hnext; hnext = t1;
        float* t2 = eacur; eacur = eanext; eanext = t2;
    }

    k_node_pool<<<(N + 63) / 64, 64, 0, stream>>>(hcur, batch, npool, cn, N);
    k_edge_pool2<<<(E + 63) / 64, 256, 0, stream>>>(eacur, ieb, rep, E);
    k_pool_merge<<<9, 256, 0, stream>>>(rep, epool, ce);
    k_head_mlp<<<G, 64, 0, stream>>>(npool, epool, cn, ce, rW1, rb1, rW2, rb2, rW3, rb3,
                                     (float*)d_out);
}

// Round 18
// 719.419 us; speedup vs baseline: 1.0136x; 1.0136x over previous
//
#include <hip/hip_runtime.h>
#include <hip/hip_bf16.h>
#include <cstdint>
#include <cstddef>

// N=20000, E=100000, G=32, HID=64, HEADS=8, HC=64, HO=512, L=3, K=4. All fp32.
// Proven: projections at N-level (Mk=WqWk^T, Me=WqWe^T; Wv/We post-agg),
// flash-fused CSR attention (reg-resident edge list, depth-1 pipelined gathers),
// R9 tile-GEMM pattern everywhere.
// R18: nf_gemm2 reverted to R12-exact (8 y-groups, plain 2-round LDS staging,
// 46.6us proven). R16/R17 prefetch variants added 10-20MB scratch traffic
// (compiler sank/spilled the prefetch regs) with no latency win — dropped.

// ---------------- embed / init ----------------

__global__ void __launch_bounds__(256) k_node_embed(
    const float* __restrict__ x, const float* __restrict__ neW, const float* __restrict__ neb,
    float* __restrict__ h, int N)
{
    int idx = blockIdx.x * 256 + threadIdx.x;
    int n = idx >> 6, c = idx & 63;
    if (n >= N) return;
    float acc = neb[c];
    #pragma unroll
    for (int j = 0; j < 7; ++j) acc += x[(size_t)n * 7 + j] * neW[j * 64 + c];
    h[(size_t)n * 64 + c] = fmaxf(acc, 0.f);
}

__global__ void __launch_bounds__(256) k_edge_w(
    const float* __restrict__ x,
    const float* __restrict__ means, const float* __restrict__ log_stds,
    const int* __restrict__ src, const int* __restrict__ dst,
    float* __restrict__ wbuf, int E)
{
    int e = blockIdx.x * 256 + threadIdx.x;
    if (e >= E) return;
    int s = src[e], d = dst[e];
    const float* ps = x + (size_t)s * 7;
    const float* pd = x + (size_t)d * 7;
    float slx = ps[0], sly = ps[1], srx = ps[2], sry = ps[3];
    float dlx = pd[0], dly = pd[1], drx = pd[2], dry = pd[3];
    float u[8];
    float rx, ry;
    rx = dlx - slx; ry = dly - sly; u[0] = sqrtf(rx*rx + ry*ry); u[1] = atan2f(ry, rx);
    rx = dlx - srx; ry = dly - sry; u[2] = sqrtf(rx*rx + ry*ry); u[3] = atan2f(ry, rx);
    rx = drx - slx; ry = dry - sly; u[4] = sqrtf(rx*rx + ry*ry); u[5] = atan2f(ry, rx);
    rx = drx - srx; ry = dry - sry; u[6] = sqrtf(rx*rx + ry*ry); u[7] = atan2f(ry, rx);
    #pragma unroll
    for (int kk = 0; kk < 4; ++kk) {
        float ssum = 0.f;
        #pragma unroll
        for (int dd = 0; dd < 8; ++dd) {
            float stdv = expf(log_stds[kk*8+dd]) + 1e-6f;
            float z = (u[dd] - means[kk*8+dd]) / stdv;
            ssum += z * z;
        }
        wbuf[(size_t)e*4 + kk] = expf(-0.5f * ssum);
    }
}

__global__ void __launch_bounds__(256) k_edge_ea(
    const float* __restrict__ edge_attr, const float* __restrict__ wbuf,
    const float* __restrict__ spW, const float* __restrict__ spb,
    const float* __restrict__ eeW, const float* __restrict__ eeb,
    float* __restrict__ ea, int E)
{
    int idx = blockIdx.x * 256 + threadIdx.x;
    int e = idx >> 6, c = idx & 63;
    if (e >= E) return;
    float acce = eeb[c];
    #pragma unroll
    for (int j = 0; j < 4; ++j) acce += edge_attr[(size_t)e*4 + j] * eeW[j*64 + c];
    float accs = spb[c];
    #pragma unroll
    for (int j = 0; j < 4; ++j) accs += wbuf[(size_t)e*4 + j] * spW[j*64 + c];
    ea[(size_t)e*64 + c] = fmaxf(acce, 0.f) + fmaxf(accs, 0.f);
}

// ---------------- CSR build ----------------

__global__ void __launch_bounds__(256) k_hist(
    const int* __restrict__ dst, int* __restrict__ deg, int E)
{
    int e = blockIdx.x * 256 + threadIdx.x;
    if (e < E) atomicAdd(deg + dst[e], 1);
}

__global__ void __launch_bounds__(1024) k_scan(
    const int* __restrict__ deg, int* __restrict__ ptr, int* __restrict__ headw, int N)
{
    __shared__ int part[1024];
    int t = threadIdx.x;
    int per = (N + 1023) / 1024;
    int s = 0;
    for (int i = 0; i < per; ++i) { int idx = t*per + i; if (idx < N) s += deg[idx]; }
    part[t] = s;
    __syncthreads();
    for (int off = 1; off < 1024; off <<= 1) {
        int v = (t >= off) ? part[t - off] : 0;
        __syncthreads();
        part[t] += v;
        __syncthreads();
    }
    int base = (t > 0) ? part[t - 1] : 0;
    for (int i = 0; i < per; ++i) {
        int idx = t*per + i;
        if (idx < N) { ptr[idx] = base; headw[idx] = base; base += deg[idx]; }
    }
    if (t == 1023) ptr[N] = part[1023];
}

__global__ void __launch_bounds__(256) k_scatter(
    const int* __restrict__ dst, const int* __restrict__ src, const int* __restrict__ batch,
    int* __restrict__ headw, int2* __restrict__ ipair, int* __restrict__ ieb, int E)
{
    int e = blockIdx.x * 256 + threadIdx.x;
    if (e < E) {
        int s = src[e];
        int pos = atomicAdd(headw + dst[e], 1);
        ipair[pos] = make_int2(s, e);
        ieb[e] = batch[s];
    }
}

// ---------------- weight precompute (all layers, hoisted) ----------------

__global__ void __launch_bounds__(256) k_wprod_all(
    const float* __restrict__ Wq, const float* __restrict__ bq,
    const float* __restrict__ Wk, const float* __restrict__ We,
    float* __restrict__ Mk, float* __restrict__ Me,
    float* __restrict__ bqk, float* __restrict__ bqe)
{
    int h = blockIdx.x;
    int which = blockIdx.y;
    int l = blockIdx.z;
    const float* Wq_l = Wq + (size_t)l * 64 * 512;
    const float* bq_l = bq + (size_t)l * 512;
    const float* Wx_l = (which ? We : Wk) + (size_t)l * 64 * 512;
    float* M  = (which ? Me : Mk) + (size_t)l * 64 * 512;
    float* bM = (which ? bqe : bqk) + (size_t)l * 512;
    __shared__ float wq_s[65][64];
    __shared__ float wx_s[64][65];
    int tid = threadIdx.x;
    for (int i = tid; i < 4096; i += 256) {
        int r = i >> 6, c2 = i & 63;
        wq_s[r][c2] = Wq_l[(size_t)r*512 + h*64 + c2];
        wx_s[r][c2] = Wx_l[(size_t)r*512 + h*64 + c2];
    }
    if (tid < 64) wq_s[64][tid] = bq_l[h*64 + tid];
    __syncthreads();
    int j = tid & 63, cg = tid >> 6;
    for (int c = cg*16; c < cg*16 + 16; ++c) {
        float s = 0.f;
        #pragma unroll 8
        for (int c2 = 0; c2 < 64; ++c2) s += wq_s[c][c2] * wx_s[j][c2];
        M[(size_t)c*512 + h*64 + j] = s;
    }
    if (tid < 64) {
        float s = 0.f;
        #pragma unroll 8
        for (int c2 = 0; c2 < 64; ++c2) s += wq_s[64][c2] * wx_s[tid][c2];
        bM[h*64 + tid] = s;
    }
}

__global__ void __launch_bounds__(64) k_wqb_all(
    const float* __restrict__ Wq, const float* __restrict__ bq,
    const float* __restrict__ bk, const float* __restrict__ be,
    float* __restrict__ wqb, float* __restrict__ cb)
{
    int l = blockIdx.x;
    const float* Wq_l = Wq + (size_t)l * 64 * 512;
    const float* bq_l = bq + (size_t)l * 512;
    const float* bk_l = bk + (size_t)l * 512;
    const float* be_l = be + (size_t)l * 512;
    float* wqb_l = wqb + (size_t)l * 512;
    float* cb_l  = cb + (size_t)l * 8;
    int c = threadIdx.x;
    for (int h = 0; h < 8; ++h) {
        float s = 0.f;
        for (int c2 = 0; c2 < 64; ++c2)
            s += Wq_l[(size_t)c*512 + h*64 + c2] * (bk_l[h*64+c2] + be_l[h*64+c2]);
        wqb_l[c*8 + h] = s;
    }
    if (c < 8) {
        float s = 0.f;
        for (int c2 = 0; c2 < 64; ++c2)
            s += bq_l[c*64 + c2] * (bk_l[c*64+c2] + be_l[c*64+c2]);
        cb_l[c] = s;
    }
}

// ---------------- projection GEMM (R9 pattern, 16 y-blocks) ----------------

__global__ void __launch_bounds__(256) k_proj16(
    const float* __restrict__ h,
    const float* __restrict__ Mk, const float* __restrict__ bqk, float* __restrict__ qk,
    const float* __restrict__ Me, const float* __restrict__ bqe, float* __restrict__ qe2,
    int N)
{
    __shared__ float As[64][132];
    __shared__ __align__(16) float Wt[64][64];
    int tid = threadIdx.x;
    int y = blockIdx.y;
    int which = y >> 3, yb = y & 7;
    const float* W    = which ? Me : Mk;
    const float* bias = (which ? bqe : bqk) + yb * 64;
    float* Y          = which ? qe2 : qk;
    int n0 = blockIdx.x * 128;
    {
        int rt = tid & 127;
        int n = n0 + rt;
        int jh = (tid >> 7) * 32;
        if (n < N) {
            const float* ap = h + (size_t)n*64;
            #pragma unroll
            for (int j4 = 0; j4 < 8; ++j4) {
                int j = jh + j4 * 4;
                float4 a = *(const float4*)(ap + j);
                As[j+0][rt] = a.x; As[j+1][rt] = a.y;
                As[j+2][rt] = a.z; As[j+3][rt] = a.w;
            }
        } else {
            #pragma unroll
            for (int j4 = 0; j4 < 8; ++j4) {
                int j = jh + j4 * 4;
                As[j+0][rt] = 0.f; As[j+1][rt] = 0.f;
                As[j+2][rt] = 0.f; As[j+3][rt] = 0.f;
            }
        }
        #pragma unroll
        for (int i = 0; i < 4; ++i) {
            int idx = tid + i * 256;
            int j = idx >> 4, c4 = (idx & 15) * 4;
            *(float4*)&Wt[j][c4] = *(const float4*)(W + (size_t)j*512 + yb*64 + c4);
        }
    }
    __syncthreads();
    int wv = tid >> 6, lane = tid & 63;
    int rg = lane >> 3, cg = lane & 7;
    int c0 = cg * 8;
    int rbase = wv * 32 + rg * 4;
    float acc[4][8];
    float4 b0 = *(const float4*)(bias + c0);
    float4 b1 = *(const float4*)(bias + c0 + 4);
    #pragma unroll
    for (int t = 0; t < 4; ++t) {
        acc[t][0]=b0.x; acc[t][1]=b0.y; acc[t][2]=b0.z; acc[t][3]=b0.w;
        acc[t][4]=b1.x; acc[t][5]=b1.y; acc[t][6]=b1.z; acc[t][7]=b1.w;
    }
    #pragma unroll 4
    for (int j = 0; j < 64; ++j) {
        float4 av = *(const float4*)&As[j][rbase];
        float4 w0 = *(const float4*)&Wt[j][c0];
        float4 w1 = *(const float4*)&Wt[j][c0 + 4];
        acc[0][0] += av.x*w0.x; acc[0][1] += av.x*w0.y; acc[0][2] += av.x*w0.z; acc[0][3] += av.x*w0.w;
        acc[0][4] += av.x*w1.x; acc[0][5] += av.x*w1.y; acc[0][6] += av.x*w1.z; acc[0][7] += av.x*w1.w;
        acc[1][0] += av.y*w0.x; acc[1][1] += av.y*w0.y; acc[1][2] += av.y*w0.z; acc[1][3] += av.y*w0.w;
        acc[1][4] += av.y*w1.x; acc[1][5] += av.y*w1.y; acc[1][6] += av.y*w1.z; acc[1][7] += av.y*w1.w;
        acc[2][0] += av.z*w0.x; acc[2][1] += av.z*w0.y; acc[2][2] += av.z*w0.z; acc[2][3] += av.z*w0.w;
        acc[2][4] += av.z*w1.x; acc[2][5] += av.z*w1.y; acc[2][6] += av.z*w1.z; acc[2][7] += av.z*w1.w;
        acc[3][0] += av.w*w0.x; acc[3][1] += av.w*w0.y; acc[3][2] += av.w*w0.z; acc[3][3] += av.w*w0.w;
        acc[3][4] += av.w*w1.x; acc[3][5] += av.w*w1.y; acc[3][6] += av.w*w1.z; acc[3][7] += av.w*w1.w;
    }
    #pragma unroll
    for (int t = 0; t < 4; ++t) {
        int n = n0 + rbase + t;
        if (n < N) {
            float4 o0 = {acc[t][0],acc[t][1],acc[t][2],acc[t][3]};
            float4 o1 = {acc[t][4],acc[t][5],acc[t][6],acc[t][7]};
            *(float4*)(Y + (size_t)n*512 + yb*64 + c0)     = o0;
            *(float4*)(Y + (size_t)n*512 + yb*64 + c0 + 4) = o1;
        }
    }
}

// ---------------- fused CSR attention (flash-style, reg-resident edge list) ----------------

__global__ void __launch_bounds__(256) k_attn_fused(
    const float* __restrict__ qk, const float* __restrict__ qe2,
    const float* __restrict__ wqb, const float* __restrict__ cb,
    const float* __restrict__ ea, const float* __restrict__ hbuf,
    const int* __restrict__ ptr, const int2* __restrict__ ipair,
    float* __restrict__ hagg, float* __restrict__ tbuf, float* __restrict__ sbuf, int N)
{
    int wv = threadIdx.x >> 6, lane = threadIdx.x & 63;
    int n = blockIdx.x * 4 + wv;
    if (n >= N) return;
    int h = lane >> 3, p = lane & 7;
    int b = ptr[n], e_ = ptr[n + 1];
    int deg = e_ - b;
    const float4* xp = (const float4*)(qk + (size_t)n*512 + lane*8);
    float4 x0 = xp[0], x1 = xp[1];
    const float4* gp = (const float4*)(qe2 + (size_t)n*512 + lane*8);
    float4 g0 = gp[0], g1 = gp[1];
    const float4* hdp = (const float4*)(hbuf + (size_t)n*64 + p*8);
    float4 hd0 = hdp[0], hd1 = hdp[1];
    float qbh = hd0.x*wqb[(p*8+0)*8+h] + hd0.y*wqb[(p*8+1)*8+h]
              + hd0.z*wqb[(p*8+2)*8+h] + hd0.w*wqb[(p*8+3)*8+h]
              + hd1.x*wqb[(p*8+4)*8+h] + hd1.y*wqb[(p*8+5)*8+h]
              + hd1.z*wqb[(p*8+6)*8+h] + hd1.w*wqb[(p*8+7)*8+h];
    qbh += __shfl_xor(qbh, 1);
    qbh += __shfl_xor(qbh, 2);
    qbh += __shfl_xor(qbh, 4);
    qbh += cb[h];
    float m = -3.4e38f, den = 0.f;
    float hacc[8], tacc[8];
    #pragma unroll
    for (int i = 0; i < 8; ++i) { hacc[i] = 0.f; tacc[i] = 0.f; }
    for (int base = 0; base < deg; base += 64) {
        int cnt = deg - base; if (cnt > 64) cnt = 64;
        int2 myp = (lane < cnt) ? ipair[b + base + lane] : make_int2(0, 0);
        int s0i = __shfl(myp.x, 0), e0i = __shfl(myp.y, 0);
        const float4* hp = (const float4*)(hbuf + (size_t)s0i*64 + p*8);
        const float4* ap = (const float4*)(ea + (size_t)e0i*64 + p*8);
        float4 h0 = hp[0], h1 = hp[1];
        float4 a0 = ap[0], a1 = ap[1];
        for (int i = 0; i < cnt; ++i) {
            float4 h0c = h0, h1c = h1, a0c = a0, a1c = a1;
            if (i + 1 < cnt) {
                int sn = __shfl(myp.x, i + 1), en = __shfl(myp.y, i + 1);
                const float4* hpn = (const float4*)(hbuf + (size_t)sn*64 + p*8);
                const float4* apn = (const float4*)(ea + (size_t)en*64 + p*8);
                h0 = hpn[0]; h1 = hpn[1]; a0 = apn[0]; a1 = apn[1];
            }
            float t = x0.x*h0c.x + x0.y*h0c.y + x0.z*h0c.z + x0.w*h0c.w
                    + x1.x*h1c.x + x1.y*h1c.y + x1.z*h1c.z + x1.w*h1c.w
                    + g0.x*a0c.x + g0.y*a0c.y + g0.z*a0c.z + g0.w*a0c.w
                    + g1.x*a1c.x + g1.y*a1c.y + g1.z*a1c.z + g1.w*a1c.w;
            t += __shfl_xor(t, 1);
            t += __shfl_xor(t, 2);
            t += __shfl_xor(t, 4);
            float al = 0.125f * (t + qbh);
            float mn = fmaxf(m, al);
            float r = expf(m - mn);
            float w = expf(al - mn);
            den = den * r + w;
            m = mn;
            hacc[0] = hacc[0]*r + w*h0c.x; hacc[1] = hacc[1]*r + w*h0c.y;
            hacc[2] = hacc[2]*r + w*h0c.z; hacc[3] = hacc[3]*r + w*h0c.w;
            hacc[4] = hacc[4]*r + w*h1c.x; hacc[5] = hacc[5]*r + w*h1c.y;
            hacc[6] = hacc[6]*r + w*h1c.z; hacc[7] = hacc[7]*r + w*h1c.w;
            tacc[0] = tacc[0]*r + w*a0c.x; tacc[1] = tacc[1]*r + w*a0c.y;
            tacc[2] = tacc[2]*r + w*a0c.z; tacc[3] = tacc[3]*r + w*a0c.w;
            tacc[4] = tacc[4]*r + w*a1c.x; tacc[5] = tacc[5]*r + w*a1c.y;
            tacc[6] = tacc[6]*r + w*a1c.z; tacc[7] = tacc[7]*r + w*a1c.w;
        }
    }
    float inv = 0.125f / (den + 1e-16f);
    float4 o;
    o = {hacc[0]*inv,hacc[1]*inv,hacc[2]*inv,hacc[3]*inv};
    *(float4*)(hagg + (size_t)n*512 + lane*8)     = o;
    o = {hacc[4]*inv,hacc[5]*inv,hacc[6]*inv,hacc[7]*inv};
    *(float4*)(hagg + (size_t)n*512 + lane*8 + 4) = o;
    o = {tacc[0]*inv,tacc[1]*inv,tacc[2]*inv,tacc[3]*inv};
    *(float4*)(tbuf + (size_t)n*512 + lane*8)     = o;
    o = {tacc[4]*inv,tacc[5]*inv,tacc[6]*inv,tacc[7]*inv};
    *(float4*)(tbuf + (size_t)n*512 + lane*8 + 4) = o;
    if (p == 0) sbuf[(size_t)n*8 + h] = den * inv;
}

// Paired partial GEMM, grid (ceil(N/128), 8): R12-exact — per block, two plain
// LDS-staged rounds: round0 = tbuf_y@We_y, round1 = hagg_y@Wv_y, same partial.
__global__ void __launch_bounds__(256) k_nf_gemm2(
    const float* __restrict__ tbuf, const float* __restrict__ hagg,
    const float* __restrict__ We, const float* __restrict__ Wv,
    float* __restrict__ pbuf, int N)
{
    __shared__ float As[64][132];
    __shared__ __align__(16) float Wt[64][64];
    int tid = threadIdx.x;
    int y = blockIdx.y;
    int n0 = blockIdx.x * 128;
    int wv = tid >> 6, lane = tid & 63;
    int rg = lane >> 3, cg = lane & 7;
    int c0 = cg * 8;
    int rbase = wv * 32 + rg * 4;
    float acc[4][8];
    #pragma unroll
    for (int t = 0; t < 4; ++t)
        #pragma unroll
        for (int i = 0; i < 8; ++i) acc[t][i] = 0.f;
    #pragma unroll
    for (int round = 0; round < 2; ++round) {
        const float* A = round ? hagg : tbuf;
        const float* W = round ? Wv : We;
        if (round) __syncthreads();
        {
            int rt = tid & 127;
            int n = n0 + rt;
            int jh = (tid >> 7) * 32;
            if (n < N) {
                const float* ap = A + (size_t)n*512 + y*64;
                #pragma unroll
                for (int j4 = 0; j4 < 8; ++j4) {
                    int j = jh + j4 * 4;
                    float4 a = *(const float4*)(ap + j);
                    As[j+0][rt] = a.x; As[j+1][rt] = a.y;
                    As[j+2][rt] = a.z; As[j+3][rt] = a.w;
                }
            } else {
                #pragma unroll
                for (int j4 = 0; j4 < 8; ++j4) {
                    int j = jh + j4 * 4;
                    As[j+0][rt] = 0.f; As[j+1][rt] = 0.f;
                    As[j+2][rt] = 0.f; As[j+3][rt] = 0.f;
                }
            }
            #pragma unroll
            for (int i = 0; i < 4; ++i) {
                int idx = tid + i * 256;
                int j = idx >> 4, c4 = (idx & 15) * 4;
                *(float4*)&Wt[j][c4] = *(const float4*)(W + (size_t)j*512 + y*64 + c4);
            }
        }
        __syncthreads();
        #pragma unroll 4
        for (int j = 0; j < 64; ++j) {
            float4 av = *(const float4*)&As[j][rbase];
            float4 w0 = *(const float4*)&Wt[j][c0];
            float4 w1 = *(const float4*)&Wt[j][c0 + 4];
            acc[0][0] += av.x*w0.x; acc[0][1] += av.x*w0.y; acc[0][2] += av.x*w0.z; acc[0][3] += av.x*w0.w;
            acc[0][4] += av.x*w1.x; acc[0][5] += av.x*w1.y; acc[0][6] += av.x*w1.z; acc[0][7] += av.x*w1.w;
            acc[1][0] += av.y*w0.x; acc[1][1] += av.y*w0.y; acc[1][2] += av.y*w0.z; acc[1][3] += av.y*w0.w;
            acc[1][4] += av.y*w1.x; acc[1][5] += av.y*w1.y; acc[1][6] += av.y*w1.z; acc[1][7] += av.y*w1.w;
            acc[2][0] += av.z*w0.x; acc[2][1] += av.z*w0.y; acc[2][2] += av.z*w0.z; acc[2][3] += av.z*w0.w;
            acc[2][4] += av.z*w1.x; acc[2][5] += av.z*w1.y; acc[2][6] += av.z*w1.z; acc[2][7] += av.z*w1.w;
            acc[3][0] += av.w*w0.x; acc[3][1] += av.w*w0.y; acc[3][2] += av.w*w0.z; acc[3][3] += av.w*w0.w;
            acc[3][4] += av.w*w1.x; acc[3][5] += av.w*w1.y; acc[3][6] += av.w*w1.z; acc[3][7] += av.w*w1.w;
        }
    }
    float* out = pbuf + (size_t)y * N * 64;
    #pragma unroll
    for (int t = 0; t < 4; ++t) {
        int n = n0 + rbase + t;
        if (n < N) {
            float4 o0 = {acc[t][0],acc[t][1],acc[t][2],acc[t][3]};
            float4 o1 = {acc[t][4],acc[t][5],acc[t][6],acc[t][7]};
            *(float4*)(out + (size_t)n*64 + c0)     = o0;
            *(float4*)(out + (size_t)n*64 + c0 + 4) = o1;
        }
    }
}

__global__ void __launch_bounds__(256) k_nf_reduce2(
    const float* __restrict__ pbuf, const float* __restrict__ hin,
    const float* __restrict__ sbuf, const float* __restrict__ Ws,
    const float* __restrict__ be, const float* __restrict__ bv,
    const float* __restrict__ bs, float* __restrict__ hnext, int N)
{
    int idx = blockIdx.x * 256 + threadIdx.x;
    int n = idx >> 6, cc = idx & 63;
    if (n >= N) return;
    float a = bs[cc];
    #pragma unroll
    for (int y = 0; y < 8; ++y) a += pbuf[(size_t)y*N*64 + (size_t)n*64 + cc];
    float hv = hin[(size_t)n*64 + cc];
    #pragma unroll 8
    for (int j = 0; j < 64; ++j) a += __shfl(hv, j) * Ws[(size_t)j*64 + cc];
    #pragma unroll
    for (int h = 0; h < 8; ++h)
        a += sbuf[(size_t)n*8 + h] * (be[h*64 + cc] + bv[h*64 + cc]);
    hnext[(size_t)n*64 + cc] = fmaxf(a, 0.f);
}

// hw[n][y*64+cc] = Σ_j h[n][j] euW[y*4096 + j*64 + cc]   grid (ceil(N/128), 2)
__global__ void __launch_bounds__(256) k_eu_pre(
    const float* __restrict__ h, const float* __restrict__ euW,
    float* __restrict__ hw, int N)
{
    __shared__ float As[64][132];
    __shared__ __align__(16) float Wt[64][64];
    int tid = threadIdx.x;
    int y = blockIdx.y;
    int n0 = blockIdx.x * 128;
    {
        int rt = tid & 127;
        int n = n0 + rt;
        int jh = (tid >> 7) * 32;
        if (n < N) {
            const float* ap = h + (size_t)n*64;
            #pragma unroll
            for (int j4 = 0; j4 < 8; ++j4) {
                int j = jh + j4 * 4;
                float4 a = *(const float4*)(ap + j);
                As[j+0][rt] = a.x; As[j+1][rt] = a.y;
                As[j+2][rt] = a.z; As[j+3][rt] = a.w;
            }
        } else {
            #pragma unroll
            for (int j4 = 0; j4 < 8; ++j4) {
                int j = jh + j4 * 4;
                As[j+0][rt] = 0.f; As[j+1][rt] = 0.f;
                As[j+2][rt] = 0.f; As[j+3][rt] = 0.f;
            }
        }
        #pragma unroll
        for (int i = 0; i < 4; ++i) {
            int idx = tid + i * 256;
            *(float4*)&Wt[idx >> 4][(idx & 15) * 4] =
                *(const float4*)(euW + (size_t)y*4096 + idx * 4);
        }
    }
    __syncthreads();
    int wv = tid >> 6, lane = tid & 63;
    int rg = lane >> 3, cg = lane & 7;
    int c0 = cg * 8;
    int rbase = wv * 32 + rg * 4;
    float acc[4][8];
    #pragma unroll
    for (int t = 0; t < 4; ++t)
        #pragma unroll
        for (int i = 0; i < 8; ++i) acc[t][i] = 0.f;
    #pragma unroll 4
    for (int j = 0; j < 64; ++j) {
        float4 av = *(const float4*)&As[j][rbase];
        float4 w0 = *(const float4*)&Wt[j][c0];
        float4 w1 = *(const float4*)&Wt[j][c0 + 4];
        acc[0][0] += av.x*w0.x; acc[0][1] += av.x*w0.y; acc[0][2] += av.x*w0.z; acc[0][3] += av.x*w0.w;
        acc[0][4] += av.x*w1.x; acc[0][5] += av.x*w1.y; acc[0][6] += av.x*w1.z; acc[0][7] += av.x*w1.w;
        acc[1][0] += av.y*w0.x; acc[1][1] += av.y*w0.y; acc[1][2] += av.y*w0.z; acc[1][3] += av.y*w0.w;
        acc[1][4] += av.y*w1.x; acc[1][5] += av.y*w1.y; acc[1][6] += av.y*w1.z; acc[1][7] += av.y*w1.w;
        acc[2][0] += av.z*w0.x; acc[2][1] += av.z*w0.y; acc[2][2] += av.z*w0.z; acc[2][3] += av.z*w0.w;
        acc[2][4] += av.z*w1.x; acc[2][5] += av.z*w1.y; acc[2][6] += av.z*w1.z; acc[2][7] += av.z*w1.w;
        acc[3][0] += av.w*w0.x; acc[3][1] += av.w*w0.y; acc[3][2] += av.w*w0.z; acc[3][3] += av.w*w0.w;
        acc[3][4] += av.w*w1.x; acc[3][5] += av.w*w1.y; acc[3][6] += av.w*w1.z; acc[3][7] += av.w*w1.w;
    }
    #pragma unroll
    for (int t = 0; t < 4; ++t) {
        int n = n0 + rbase + t;
        if (n < N) {
            float4 o0 = {acc[t][0],acc[t][1],acc[t][2],acc[t][3]};
            float4 o1 = {acc[t][4],acc[t][5],acc[t][6],acc[t][7]};
            *(float4*)(hw + (size_t)n*128 + y*64 + c0)     = o0;
            *(float4*)(hw + (size_t)n*128 + y*64 + c0 + 4) = o1;
        }
    }
}

// ea2 = relu( hw[src][0:64] + hw[dst][64:128] + ea@W3 + eub )
__global__ void __launch_bounds__(256) k_edge_update2(
    const float* __restrict__ hw, const float* __restrict__ ea,
    const float* __restrict__ euW2, const float* __restrict__ eub,
    const int* __restrict__ src, const int* __restrict__ dst,
    float* __restrict__ ea2, int E)
{
    __shared__ float As[64][132];
    __shared__ __align__(16) float Wt[64][64];
    __shared__ int sid[128], did[128];
    int tid = threadIdx.x;
    int e0 = blockIdx.x * 128;
    if (tid < 128) {
        int e = e0 + tid; if (e >= E) e = E - 1;
        sid[tid] = src[e]; did[tid] = dst[e];
    }
    {
        int et = tid & 127;
        int e = e0 + et; if (e >= E) e = E - 1;
        const float* ap = ea + (size_t)e * 64;
        int jh = (tid >> 7) * 32;
        #pragma unroll
        for (int j4 = 0; j4 < 8; ++j4) {
            int j = jh + j4 * 4;
            float4 a = *(const float4*)(ap + j);
            As[j+0][et] = a.x; As[j+1][et] = a.y;
            As[j+2][et] = a.z; As[j+3][et] = a.w;
        }
        #pragma unroll
        for (int i = 0; i < 4; ++i) {
            int idx = tid + i * 256;
            *(float4*)&Wt[idx >> 4][(idx & 15) * 4] = *(const float4*)(euW2 + idx * 4);
        }
    }
    __syncthreads();
    int wv = tid >> 6, lane = tid & 63;
    int rg = lane >> 3, cg = lane & 7;
    int c0 = cg * 8;
    int rbase = wv * 32 + rg * 4;
    float acc[4][8];
    float4 b0 = *(const float4*)(eub + c0);
    float4 b1 = *(const float4*)(eub + c0 + 4);
    #pragma unroll
    for (int t = 0; t < 4; ++t) {
        acc[t][0]=b0.x; acc[t][1]=b0.y; acc[t][2]=b0.z; acc[t][3]=b0.w;
        acc[t][4]=b1.x; acc[t][5]=b1.y; acc[t][6]=b1.z; acc[t][7]=b1.w;
    }
    #pragma unroll 4
    for (int j = 0; j < 64; ++j) {
        float4 av = *(const float4*)&As[j][rbase];
        float4 w0 = *(const float4*)&Wt[j][c0];
        float4 w1 = *(const float4*)&Wt[j][c0 + 4];
        acc[0][0] += av.x*w0.x; acc[0][1] += av.x*w0.y; acc[0][2] += av.x*w0.z; acc[0][3] += av.x*w0.w;
        acc[0][4] += av.x*w1.x; acc[0][5] += av.x*w1.y; acc[0][6] += av.x*w1.z; acc[0][7] += av.x*w1.w;
        acc[1][0] += av.y*w0.x; acc[1][1] += av.y*w0.y; acc[1][2] += av.y*w0.z; acc[1][3] += av.y*w0.w;
        acc[1][4] += av.y*w1.x; acc[1][5] += av.y*w1.y; acc[1][6] += av.y*w1.z; acc[1][7] += av.y*w1.w;
        acc[2][0] += av.z*w0.x; acc[2][1] += av.z*w0.y; acc[2][2] += av.z*w0.z; acc[2][3] += av.z*w0.w;
        acc[2][4] += av.z*w1.x; acc[2][5] += av.z*w1.y; acc[2][6] += av.z*w1.z; acc[2][7] += av.z*w1.w;
        acc[3][0] += av.w*w0.x; acc[3][1] += av.w*w0.y; acc[3][2] += av.w*w0.z; acc[3][3] += av.w*w0.w;
        acc[3][4] += av.w*w1.x; acc[3][5] += av.w*w1.y; acc[3][6] += av.w*w1.z; acc[3][7] += av.w*w1.w;
    }
    #pragma unroll
    for (int t = 0; t < 4; ++t) {
        int e = e0 + rbase + t;
        if (e < E) {
            int s = sid[rbase + t], d = did[rbase + t];
            const float4* sp = (const float4*)(hw + (size_t)s*128 + c0);
            const float4* dp = (const float4*)(hw + (size_t)d*128 + 64 + c0);
            float4 s0 = sp[0], s1 = sp[1];
            float4 d0 = dp[0], d1 = dp[1];
            float4 o0 = {fmaxf(acc[t][0]+s0.x+d0.x,0.f), fmaxf(acc[t][1]+s0.y+d0.y,0.f),
                         fmaxf(acc[t][2]+s0.z+d0.z,0.f), fmaxf(acc[t][3]+s0.w+d0.w,0.f)};
            float4 o1 = {fmaxf(acc[t][4]+s1.x+d1.x,0.f), fmaxf(acc[t][5]+s1.y+d1.y,0.f),
                         fmaxf(acc[t][6]+s1.z+d1.z,0.f), fmaxf(acc[t][7]+s1.w+d1.w,0.f)};
            *(float4*)(ea2 + (size_t)e*64 + c0)     = o0;
            *(float4*)(ea2 + (size_t)e*64 + c0 + 4) = o1;
        }
    }
}

// ---------------- pooling / head ----------------

__global__ void __launch_bounds__(64) k_node_pool(
    const float* __restrict__ h, const int* __restrict__ batch,
    float* __restrict__ npool, float* __restrict__ cn, int N)
{
    int lane = threadIdx.x;
    int n0 = blockIdx.x * 64;
    float acc = 0.f; int cur = -1; int run = 0;
    for (int i = 0; i < 64; ++i) {
        int n = n0 + i;
        if (n >= N) break;
        int b = batch[n];
        if (b != cur) {
            if (cur >= 0) {
                atomicAdd(npool + (size_t)cur*64 + lane, acc);
                if (lane == 0) atomicAdd(cn + cur, (float)run);
            }
            cur = b; acc = 0.f; run = 0;
        }
        acc += h[(size_t)n*64 + lane];
        ++run;
    }
    if (cur >= 0) {
        atomicAdd(npool + (size_t)cur*64 + lane, acc);
        if (lane == 0) atomicAdd(cn + cur, (float)run);
    }
}

__global__ void __launch_bounds__(256) k_edge_pool2(
    const float* __restrict__ ea, const int* __restrict__ ieb,
    float* __restrict__ rep, int E)
{
    __shared__ float pool_s[32][64];
    __shared__ float cnt_s[32];
    int tid = threadIdx.x;
    for (int i = tid; i < 2048; i += 256) ((float*)pool_s)[i] = 0.f;
    if (tid < 32) cnt_s[tid] = 0.f;
    __syncthreads();
    int wv = tid >> 6, lane = tid & 63;
    int base = blockIdx.x * 64 + wv * 16;
    int b16[16]; float v16[16];
    #pragma unroll
    for (int u = 0; u < 16; ++u) {
        int e = base + u;
        bool ok = (e < E);
        b16[u] = ok ? ieb[e] : -1;
        v16[u] = ok ? ea[(size_t)e*64 + lane] : 0.f;
    }
    #pragma unroll
    for (int u = 0; u < 16; ++u) {
        if (b16[u] >= 0) {
            atomicAdd(&pool_s[b16[u]][lane], v16[u]);
            if (lane == 0) atomicAdd(&cnt_s[b16[u]], 1.f);
        }
    }
    __syncthreads();
    float* myrep = rep + (size_t)(blockIdx.x & 7) * 2080;
    for (int i = tid; i < 2048; i += 256) atomicAdd(myrep + i, ((float*)pool_s)[i]);
    if (tid < 32) atomicAdd(myrep + 2048 + tid, cnt_s[tid]);
}

__global__ void __launch_bounds__(256) k_pool_merge(
    const float* __restrict__ rep, float* __restrict__ epool, float* __restrict__ ce)
{
    int i = blockIdx.x * 256 + threadIdx.x;
    if (i < 2080) {
        float s = 0.f;
        #pragma unroll
        for (int r = 0; r < 8; ++r) s += rep[(size_t)r*2080 + i];
        if (i < 2048) epool[i] = s; else ce[i - 2048] = s;
    }
}

__global__ void __launch_bounds__(64) k_head_mlp(
    const float* __restrict__ npool, const float* __restrict__ epool,
    const float* __restrict__ cn, const float* __restrict__ ce,
    const float* __restrict__ rW1, const float* __restrict__ rb1,
    const float* __restrict__ rW2, const float* __restrict__ rb2,
    const float* __restrict__ rW3, const float* __restrict__ rb3,
    float* __restrict__ out)
{
    __shared__ float g[128];
    __shared__ float h1[64];
    __shared__ float h2[64];
    int b = blockIdx.x, lane = threadIdx.x;
    float cnv = fmaxf(cn[b], 1.f), cev = fmaxf(ce[b], 1.f);
    g[lane]      = npool[(size_t)b*64 + lane] / cnv;
    g[64 + lane] = epool[(size_t)b*64 + lane] / cev;
    __syncthreads();
    float acc = rb1[lane];
    #pragma unroll 4
    for (int j = 0; j < 128; ++j) acc += g[j] * rW1[j*64 + lane];
    h1[lane] = fmaxf(acc, 0.f);
    __syncthreads();
    acc = rb2[lane];
    #pragma unroll 4
    for (int j = 0; j < 64; ++j) acc += h1[j] * rW2[j*64 + lane];
    h2[lane] = fmaxf(acc, 0.f);
    __syncthreads();
    if (lane < 2) {
        float o = rb3[lane];
        for (int j = 0; j < 64; ++j) o += h2[j] * rW3[j*2 + lane];
        out[b*2 + lane] = tanhf(o);
    }
}

// ---------------- launcher ----------------

extern "C" void kernel_launch(void* const* d_in, const int* in_sizes, int n_in,
                              void* d_out, int out_size, void* d_ws, size_t ws_size,
                              hipStream_t stream)
{
    const float* x         = (const float*)d_in[0];
    const float* edge_attr = (const float*)d_in[1];
    const float* means     = (const float*)d_in[2];
    const float* log_stds  = (const float*)d_in[3];
    const float* spW       = (const float*)d_in[4];
    const float* spb       = (const float*)d_in[5];
    const float* neW       = (const float*)d_in[6];
    const float* neb       = (const float*)d_in[7];
    const float* eeW       = (const float*)d_in[8];
    const float* eeb       = (const float*)d_in[9];
    const float* Wq        = (const float*)d_in[10];
    const float* bq        = (const float*)d_in[11];
    const float* Wk        = (const float*)d_in[12];
    const float* bk        = (const float*)d_in[13];
    const float* Wv        = (const float*)d_in[14];
    const float* bv        = (const float*)d_in[15];
    const float* We        = (const float*)d_in[16];
    const float* be        = (const float*)d_in[17];
    const float* Ws        = (const float*)d_in[18];
    const float* bs        = (const float*)d_in[19];
    const float* euW       = (const float*)d_in[20];
    const float* eub       = (const float*)d_in[21];
    const float* rW1       = (const float*)d_in[22];
    const float* rb1       = (const float*)d_in[23];
    const float* rW2       = (const float*)d_in[24];
    const float* rb2       = (const float*)d_in[25];
    const float* rW3       = (const float*)d_in[26];
    const float* rb3       = (const float*)d_in[27];
    const int* eidx        = (const int*)d_in[28];
    const int* batch       = (const int*)d_in[29];

    int N = in_sizes[0] / 7;
    int E = in_sizes[1] / 4;
    const int G = 32;
    const int* srcp = eidx;
    const int* dstp = eidx + E;

    float* ws = (float*)d_ws;
    size_t fl = 0;
    float* hA    = ws + fl; fl += (size_t)N * 64;
    float* hB    = ws + fl; fl += (size_t)N * 64;
    float* eaA   = ws + fl; fl += (size_t)E * 64;
    float* eaB   = ws + fl; fl += (size_t)E * 64;
    float* B1    = ws + fl; fl += (size_t)N * 512;   // qk -> hagg
    float* B2    = ws + fl; fl += (size_t)N * 512;   // qe2 -> tbuf
    float* B3    = ws + fl; fl += (size_t)N * 512;   // pbuf (8 x N64), then hw (N x 128)
    float* alpha = ws + fl; fl += (size_t)E * 8;     // wbuf (E*4) at init only
    float* sbuf  = ws + fl; fl += (size_t)N * 8;
    float* npool = ws + fl; fl += (size_t)G * 64;
    float* epool = ws + fl; fl += (size_t)G * 64;
    float* cn    = ws + fl; fl += G;
    float* ce    = ws + fl; fl += G;
    float* Mk3   = ws + fl; fl += 3 * 64 * 512;
    float* Me3   = ws + fl; fl += 3 * 64 * 512;
    float* bqk3  = ws + fl; fl += 3 * 512;
    float* bqe3  = ws + fl; fl += 3 * 512;
    float* wqb3  = ws + fl; fl += 3 * 512;
    float* cb3   = ws + fl; fl += 24;
    float* rep   = ws + fl; fl += 8 * 2080;
    int* ideg  = (int*)(ws + fl); fl += (size_t)N;
    int* ihead = (int*)(ws + fl); fl += (size_t)N;
    int2* ipair = (int2*)(ws + fl); fl += (size_t)E * 2;   // 8B-aligned (even offset)
    int* ieb   = (int*)(ws + fl); fl += (size_t)E;
    int* iptr  = (int*)(ws + fl); fl += (size_t)N + 1;
    // ~47.9M floats = 191.5 MB (ws known >= ~194 MB)

    float* wbuf = alpha;

    hipMemsetAsync(npool, 0, (size_t)(G * 130) * sizeof(float), stream);
    hipMemsetAsync(rep, 0, (size_t)(8 * 2080) * sizeof(float), stream);
    hipMemsetAsync(ideg, 0, (size_t)N * sizeof(int), stream);

    k_node_embed<<<(N * 64 + 255) / 256, 256, 0, stream>>>(x, neW, neb, hA, N);
    k_edge_w<<<(E + 255) / 256, 256, 0, stream>>>(x, means, log_stds, srcp, dstp, wbuf, E);
    k_edge_ea<<<((size_t)E * 64 + 255) / 256, 256, 0, stream>>>(edge_attr, wbuf,
                                                                spW, spb, eeW, eeb, eaA, E);
    k_hist<<<(E + 255) / 256, 256, 0, stream>>>(dstp, ideg, E);
    k_scan<<<1, 1024, 0, stream>>>(ideg, iptr, ihead, N);
    k_scatter<<<(E + 255) / 256, 256, 0, stream>>>(dstp, srcp, batch, ihead, ipair, ieb, E);
    k_wprod_all<<<dim3(8, 2, 3), 256, 0, stream>>>(Wq, bq, Wk, We, Mk3, Me3, bqk3, bqe3);
    k_wqb_all<<<3, 64, 0, stream>>>(Wq, bq, bk, be, wqb3, cb3);

    float* hcur = hA;  float* hnext = hB;
    float* eacur = eaA; float* eanext = eaB;
    for (int l = 0; l < 3; ++l) {
        const float* Wv_l = Wv + (size_t)l * 64 * 512;
        const float* We_l = We + (size_t)l * 64 * 512;
        const float* bv_l = bv + (size_t)l * 512;
        const float* be_l = be + (size_t)l * 512;
        const float* euW_l = euW + (size_t)l * 192 * 64;

        k_proj16<<<dim3((N + 127) / 128, 16), 256, 0, stream>>>(
            hcur,
            Mk3 + (size_t)l * 32768, bqk3 + (size_t)l * 512, B1,
            Me3 + (size_t)l * 32768, bqe3 + (size_t)l * 512, B2, N);

        k_attn_fused<<<(N + 3) / 4, 256, 0, stream>>>(B1, B2,
                                                      wqb3 + (size_t)l * 512,
                                                      cb3 + (size_t)l * 8,
                                                      eacur, hcur,
                                                      iptr, ipair,
                                                      B1 /*hagg*/, B2 /*tbuf*/, sbuf, N);
        k_nf_gemm2<<<dim3((N + 127) / 128, 8), 256, 0, stream>>>(B2, B1, We_l, Wv_l, B3, N);
        k_nf_reduce2<<<((size_t)N * 64 + 255) / 256, 256, 0, stream>>>(B3, hcur, sbuf,
                                                                       Ws + (size_t)l * 64 * 64,
                                                                       be_l, bv_l,
                                                                       bs + (size_t)l * 64,
                                                                       hnext, N);
        k_eu_pre<<<dim3((N + 127) / 128, 2), 256, 0, stream>>>(hnext, euW_l, B3, N);
        k_edge_update2<<<(E + 127) / 128, 256, 0, stream>>>(B3, eacur, euW_l + 2 * 4096,
                                                            eub + (size_t)l * 64,
                                                            srcp, dstp, eanext, E);
        float* t1 = hcur; hcur = hnext; hnext = t1;
        float* t2 = eacur; eacur = eanext; eanext = t2;
    }

    k_node_pool<<<(N + 63) / 64, 64, 0, stream>>>(hcur, batch, npool, cn, N);
    k_edge_pool2<<<(E + 63) / 64, 256, 0, stream>>>(eacur, ieb, rep, E);
    k_pool_merge<<<9, 256, 0, stream>>>(rep, epool, ce);
    k_head_mlp<<<G, 64, 0, stream>>>(npool, epool, cn, ce, rW1, rb1, rW2, rb2, rW3, rb3,
                                     (float*)d_out);
}

// Round 19
// 716.600 us; speedup vs baseline: 1.0176x; 1.0039x over previous
//
#include <hip/hip_runtime.h>
#include <hip/hip_bf16.h>
#include <cstdint>
#include <cstddef>

// N=20000, E=100000, G=32, HID=64, HEADS=8, HC=64, HO=512, L=3, K=4. All fp32.
// Proven: projections at N-level (Mk=WqWk^T, Me=WqWe^T; Wv/We post-agg),
// flash-fused CSR attention, R9 tile-GEMM pattern, R12 nf_gemm2.
// R19: ea pipeline switched to CSR SLOT ORDER. Each node's slots are contiguous,
// so attention's ea reads become streaming (was a random 256B gather per edge).
// edge_w/edge_ea/edge_update2/edge_pool all operate on slots; edge_attr (input)
// is the only edge-indexed access left (16B/edge prologue gather). h[src] is
// the only gather remaining in attention (5MB, L2-resident).

// ---------------- embed / init ----------------

__global__ void __launch_bounds__(256) k_node_embed(
    const float* __restrict__ x, const float* __restrict__ neW, const float* __restrict__ neb,
    float* __restrict__ h, int N)
{
    int idx = blockIdx.x * 256 + threadIdx.x;
    int n = idx >> 6, c = idx & 63;
    if (n >= N) return;
    float acc = neb[c];
    #pragma unroll
    for (int j = 0; j < 7; ++j) acc += x[(size_t)n * 7 + j] * neW[j * 64 + c];
    h[(size_t)n * 64 + c] = fmaxf(acc, 0.f);
}

// slot-based: geometry weights written to wbuf[slot*4+k] (coalesced)
__global__ void __launch_bounds__(256) k_edge_w(
    const float* __restrict__ x,
    const float* __restrict__ means, const float* __restrict__ log_stds,
    const int2* __restrict__ ipair, const int* __restrict__ idst,
    float* __restrict__ wbuf, int E)
{
    int slot = blockIdx.x * 256 + threadIdx.x;
    if (slot >= E) return;
    int s = ipair[slot].x, d = idst[slot];
    const float* ps = x + (size_t)s * 7;
    const float* pd = x + (size_t)d * 7;
    float slx = ps[0], sly = ps[1], srx = ps[2], sry = ps[3];
    float dlx = pd[0], dly = pd[1], drx = pd[2], dry = pd[3];
    float u[8];
    float rx, ry;
    rx = dlx - slx; ry = dly - sly; u[0] = sqrtf(rx*rx + ry*ry); u[1] = atan2f(ry, rx);
    rx = dlx - srx; ry = dly - sry; u[2] = sqrtf(rx*rx + ry*ry); u[3] = atan2f(ry, rx);
    rx = drx - slx; ry = dry - sly; u[4] = sqrtf(rx*rx + ry*ry); u[5] = atan2f(ry, rx);
    rx = drx - srx; ry = dry - sry; u[6] = sqrtf(rx*rx + ry*ry); u[7] = atan2f(ry, rx);
    #pragma unroll
    for (int kk = 0; kk < 4; ++kk) {
        float ssum = 0.f;
        #pragma unroll
        for (int dd = 0; dd < 8; ++dd) {
            float stdv = expf(log_stds[kk*8+dd]) + 1e-6f;
            float z = (u[dd] - means[kk*8+dd]) / stdv;
            ssum += z * z;
        }
        wbuf[(size_t)slot*4 + kk] = expf(-0.5f * ssum);
    }
}

// slot-based: ea[slot][c]; edge_attr gathered via e=ipair[slot].y (16B broadcast)
__global__ void __launch_bounds__(256) k_edge_ea(
    const float* __restrict__ edge_attr, const float* __restrict__ wbuf,
    const int2* __restrict__ ipair,
    const float* __restrict__ spW, const float* __restrict__ spb,
    const float* __restrict__ eeW, const float* __restrict__ eeb,
    float* __restrict__ ea, int E)
{
    int idx = blockIdx.x * 256 + threadIdx.x;
    int slot = idx >> 6, c = idx & 63;
    if (slot >= E) return;
    int e = ipair[slot].y;
    float acce = eeb[c];
    #pragma unroll
    for (int j = 0; j < 4; ++j) acce += edge_attr[(size_t)e*4 + j] * eeW[j*64 + c];
    float accs = spb[c];
    #pragma unroll
    for (int j = 0; j < 4; ++j) accs += wbuf[(size_t)slot*4 + j] * spW[j*64 + c];
    ea[(size_t)slot*64 + c] = fmaxf(acce, 0.f) + fmaxf(accs, 0.f);
}

// ---------------- CSR build ----------------

__global__ void __launch_bounds__(256) k_hist(
    const int* __restrict__ dst, int* __restrict__ deg, int E)
{
    int e = blockIdx.x * 256 + threadIdx.x;
    if (e < E) atomicAdd(deg + dst[e], 1);
}

__global__ void __launch_bounds__(1024) k_scan(
    const int* __restrict__ deg, int* __restrict__ ptr, int* __restrict__ headw, int N)
{
    __shared__ int part[1024];
    int t = threadIdx.x;
    int per = (N + 1023) / 1024;
    int s = 0;
    for (int i = 0; i < per; ++i) { int idx = t*per + i; if (idx < N) s += deg[idx]; }
    part[t] = s;
    __syncthreads();
    for (int off = 1; off < 1024; off <<= 1) {
        int v = (t >= off) ? part[t - off] : 0;
        __syncthreads();
        part[t] += v;
        __syncthreads();
    }
    int base = (t > 0) ? part[t - 1] : 0;
    for (int i = 0; i < per; ++i) {
        int idx = t*per + i;
        if (idx < N) { ptr[idx] = base; headw[idx] = base; base += deg[idx]; }
    }
    if (t == 1023) ptr[N] = part[1023];
}

// ipair[pos]=(src,e), idst[pos]=dst, iebs[pos]=batch[src]
__global__ void __launch_bounds__(256) k_scatter(
    const int* __restrict__ dst, const int* __restrict__ src, const int* __restrict__ batch,
    int* __restrict__ headw, int2* __restrict__ ipair, int* __restrict__ idst,
    int* __restrict__ iebs, int E)
{
    int e = blockIdx.x * 256 + threadIdx.x;
    if (e < E) {
        int s = src[e];
        int d = dst[e];
        int pos = atomicAdd(headw + d, 1);
        ipair[pos] = make_int2(s, e);
        idst[pos] = d;
        iebs[pos] = batch[s];
    }
}

// ---------------- weight precompute (all layers, hoisted) ----------------

__global__ void __launch_bounds__(256) k_wprod_all(
    const float* __restrict__ Wq, const float* __restrict__ bq,
    const float* __restrict__ Wk, const float* __restrict__ We,
    float* __restrict__ Mk, float* __restrict__ Me,
    float* __restrict__ bqk, float* __restrict__ bqe)
{
    int h = blockIdx.x;
    int which = blockIdx.y;
    int l = blockIdx.z;
    const float* Wq_l = Wq + (size_t)l * 64 * 512;
    const float* bq_l = bq + (size_t)l * 512;
    const float* Wx_l = (which ? We : Wk) + (size_t)l * 64 * 512;
    float* M  = (which ? Me : Mk) + (size_t)l * 64 * 512;
    float* bM = (which ? bqe : bqk) + (size_t)l * 512;
    __shared__ float wq_s[65][64];
    __shared__ float wx_s[64][65];
    int tid = threadIdx.x;
    for (int i = tid; i < 4096; i += 256) {
        int r = i >> 6, c2 = i & 63;
        wq_s[r][c2] = Wq_l[(size_t)r*512 + h*64 + c2];
        wx_s[r][c2] = Wx_l[(size_t)r*512 + h*64 + c2];
    }
    if (tid < 64) wq_s[64][tid] = bq_l[h*64 + tid];
    __syncthreads();
    int j = tid & 63, cg = tid >> 6;
    for (int c = cg*16; c < cg*16 + 16; ++c) {
        float s = 0.f;
        #pragma unroll 8
        for (int c2 = 0; c2 < 64; ++c2) s += wq_s[c][c2] * wx_s[j][c2];
        M[(size_t)c*512 + h*64 + j] = s;
    }
    if (tid < 64) {
        float s = 0.f;
        #pragma unroll 8
        for (int c2 = 0; c2 < 64; ++c2) s += wq_s[64][c2] * wx_s[tid][c2];
        bM[h*64 + tid] = s;
    }
}

__global__ void __launch_bounds__(64) k_wqb_all(
    const float* __restrict__ Wq, const float* __restrict__ bq,
    const float* __restrict__ bk, const float* __restrict__ be,
    float* __restrict__ wqb, float* __restrict__ cb)
{
    int l = blockIdx.x;
    const float* Wq_l = Wq + (size_t)l * 64 * 512;
    const float* bq_l = bq + (size_t)l * 512;
    const float* bk_l = bk + (size_t)l * 512;
    const float* be_l = be + (size_t)l * 512;
    float* wqb_l = wqb + (size_t)l * 512;
    float* cb_l  = cb + (size_t)l * 8;
    int c = threadIdx.x;
    for (int h = 0; h < 8; ++h) {
        float s = 0.f;
        for (int c2 = 0; c2 < 64; ++c2)
            s += Wq_l[(size_t)c*512 + h*64 + c2] * (bk_l[h*64+c2] + be_l[h*64+c2]);
        wqb_l[c*8 + h] = s;
    }
    if (c < 8) {
        float s = 0.f;
        for (int c2 = 0; c2 < 64; ++c2)
            s += bq_l[c*64 + c2] * (bk_l[c*64+c2] + be_l[c*64+c2]);
        cb_l[c] = s;
    }
}

// ---------------- projection GEMM (R9 pattern, 16 y-blocks) ----------------

__global__ void __launch_bounds__(256) k_proj16(
    const float* __restrict__ h,
    const float* __restrict__ Mk, const float* __restrict__ bqk, float* __restrict__ qk,
    const float* __restrict__ Me, const float* __restrict__ bqe, float* __restrict__ qe2,
    int N)
{
    __shared__ float As[64][132];
    __shared__ __align__(16) float Wt[64][64];
    int tid = threadIdx.x;
    int y = blockIdx.y;
    int which = y >> 3, yb = y & 7;
    const float* W    = which ? Me : Mk;
    const float* bias = (which ? bqe : bqk) + yb * 64;
    float* Y          = which ? qe2 : qk;
    int n0 = blockIdx.x * 128;
    {
        int rt = tid & 127;
        int n = n0 + rt;
        int jh = (tid >> 7) * 32;
        if (n < N) {
            const float* ap = h + (size_t)n*64;
            #pragma unroll
            for (int j4 = 0; j4 < 8; ++j4) {
                int j = jh + j4 * 4;
                float4 a = *(const float4*)(ap + j);
                As[j+0][rt] = a.x; As[j+1][rt] = a.y;
                As[j+2][rt] = a.z; As[j+3][rt] = a.w;
            }
        } else {
            #pragma unroll
            for (int j4 = 0; j4 < 8; ++j4) {
                int j = jh + j4 * 4;
                As[j+0][rt] = 0.f; As[j+1][rt] = 0.f;
                As[j+2][rt] = 0.f; As[j+3][rt] = 0.f;
            }
        }
        #pragma unroll
        for (int i = 0; i < 4; ++i) {
            int idx = tid + i * 256;
            int j = idx >> 4, c4 = (idx & 15) * 4;
            *(float4*)&Wt[j][c4] = *(const float4*)(W + (size_t)j*512 + yb*64 + c4);
        }
    }
    __syncthreads();
    int wv = tid >> 6, lane = tid & 63;
    int rg = lane >> 3, cg = lane & 7;
    int c0 = cg * 8;
    int rbase = wv * 32 + rg * 4;
    float acc[4][8];
    float4 b0 = *(const float4*)(bias + c0);
    float4 b1 = *(const float4*)(bias + c0 + 4);
    #pragma unroll
    for (int t = 0; t < 4; ++t) {
        acc[t][0]=b0.x; acc[t][1]=b0.y; acc[t][2]=b0.z; acc[t][3]=b0.w;
        acc[t][4]=b1.x; acc[t][5]=b1.y; acc[t][6]=b1.z; acc[t][7]=b1.w;
    }
    #pragma unroll 4
    for (int j = 0; j < 64; ++j) {
        float4 av = *(const float4*)&As[j][rbase];
        float4 w0 = *(const float4*)&Wt[j][c0];
        float4 w1 = *(const float4*)&Wt[j][c0 + 4];
        acc[0][0] += av.x*w0.x; acc[0][1] += av.x*w0.y; acc[0][2] += av.x*w0.z; acc[0][3] += av.x*w0.w;
        acc[0][4] += av.x*w1.x; acc[0][5] += av.x*w1.y; acc[0][6] += av.x*w1.z; acc[0][7] += av.x*w1.w;
        acc[1][0] += av.y*w0.x; acc[1][1] += av.y*w0.y; acc[1][2] += av.y*w0.z; acc[1][3] += av.y*w0.w;
        acc[1][4] += av.y*w1.x; acc[1][5] += av.y*w1.y; acc[1][6] += av.y*w1.z; acc[1][7] += av.y*w1.w;
        acc[2][0] += av.z*w0.x; acc[2][1] += av.z*w0.y; acc[2][2] += av.z*w0.z; acc[2][3] += av.z*w0.w;
        acc[2][4] += av.z*w1.x; acc[2][5] += av.z*w1.y; acc[2][6] += av.z*w1.z; acc[2][7] += av.z*w1.w;
        acc[3][0] += av.w*w0.x; acc[3][1] += av.w*w0.y; acc[3][2] += av.w*w0.z; acc[3][3] += av.w*w0.w;
        acc[3][4] += av.w*w1.x; acc[3][5] += av.w*w1.y; acc[3][6] += av.w*w1.z; acc[3][7] += av.w*w1.w;
    }
    #pragma unroll
    for (int t = 0; t < 4; ++t) {
        int n = n0 + rbase + t;
        if (n < N) {
            float4 o0 = {acc[t][0],acc[t][1],acc[t][2],acc[t][3]};
            float4 o1 = {acc[t][4],acc[t][5],acc[t][6],acc[t][7]};
            *(float4*)(Y + (size_t)n*512 + yb*64 + c0)     = o0;
            *(float4*)(Y + (size_t)n*512 + yb*64 + c0 + 4) = o1;
        }
    }
}

// ---------------- fused CSR attention (slot-ordered ea: streaming reads) ----------------

__global__ void __launch_bounds__(256) k_attn_fused(
    const float* __restrict__ qk, const float* __restrict__ qe2,
    const float* __restrict__ wqb, const float* __restrict__ cb,
    const float* __restrict__ ea, const float* __restrict__ hbuf,
    const int* __restrict__ ptr, const int2* __restrict__ ipair,
    float* __restrict__ hagg, float* __restrict__ tbuf, float* __restrict__ sbuf, int N)
{
    int wv = threadIdx.x >> 6, lane = threadIdx.x & 63;
    int n = blockIdx.x * 4 + wv;
    if (n >= N) return;
    int h = lane >> 3, p = lane & 7;
    int b = ptr[n], e_ = ptr[n + 1];
    int deg = e_ - b;
    const float4* xp = (const float4*)(qk + (size_t)n*512 + lane*8);
    float4 x0 = xp[0], x1 = xp[1];
    const float4* gp = (const float4*)(qe2 + (size_t)n*512 + lane*8);
    float4 g0 = gp[0], g1 = gp[1];
    const float4* hdp = (const float4*)(hbuf + (size_t)n*64 + p*8);
    float4 hd0 = hdp[0], hd1 = hdp[1];
    float qbh = hd0.x*wqb[(p*8+0)*8+h] + hd0.y*wqb[(p*8+1)*8+h]
              + hd0.z*wqb[(p*8+2)*8+h] + hd0.w*wqb[(p*8+3)*8+h]
              + hd1.x*wqb[(p*8+4)*8+h] + hd1.y*wqb[(p*8+5)*8+h]
              + hd1.z*wqb[(p*8+6)*8+h] + hd1.w*wqb[(p*8+7)*8+h];
    qbh += __shfl_xor(qbh, 1);
    qbh += __shfl_xor(qbh, 2);
    qbh += __shfl_xor(qbh, 4);
    qbh += cb[h];
    float m = -3.4e38f, den = 0.f;
    float hacc[8], tacc[8];
    #pragma unroll
    for (int i = 0; i < 8; ++i) { hacc[i] = 0.f; tacc[i] = 0.f; }
    for (int base = 0; base < deg; base += 64) {
        int cnt = deg - base; if (cnt > 64) cnt = 64;
        int2 myp = (lane < cnt) ? ipair[b + base + lane] : make_int2(0, 0);
        int s0i = __shfl(myp.x, 0);
        const float4* hp = (const float4*)(hbuf + (size_t)s0i*64 + p*8);
        const float4* ap = (const float4*)(ea + (size_t)(b + base)*64 + p*8);
        float4 h0 = hp[0], h1 = hp[1];
        float4 a0 = ap[0], a1 = ap[1];
        for (int i = 0; i < cnt; ++i) {
            float4 h0c = h0, h1c = h1, a0c = a0, a1c = a1;
            if (i + 1 < cnt) {
                int sn = __shfl(myp.x, i + 1);
                const float4* hpn = (const float4*)(hbuf + (size_t)sn*64 + p*8);
                const float4* apn = (const float4*)(ea + (size_t)(b + base + i + 1)*64 + p*8);
                h0 = hpn[0]; h1 = hpn[1]; a0 = apn[0]; a1 = apn[1];
            }
            float t = x0.x*h0c.x + x0.y*h0c.y + x0.z*h0c.z + x0.w*h0c.w
                    + x1.x*h1c.x + x1.y*h1c.y + x1.z*h1c.z + x1.w*h1c.w
                    + g0.x*a0c.x + g0.y*a0c.y + g0.z*a0c.z + g0.w*a0c.w
                    + g1.x*a1c.x + g1.y*a1c.y + g1.z*a1c.z + g1.w*a1c.w;
            t += __shfl_xor(t, 1);
            t += __shfl_xor(t, 2);
            t += __shfl_xor(t, 4);
            float al = 0.125f * (t + qbh);
            float mn = fmaxf(m, al);
            float r = expf(m - mn);
            float w = expf(al - mn);
            den = den * r + w;
            m = mn;
            hacc[0] = hacc[0]*r + w*h0c.x; hacc[1] = hacc[1]*r + w*h0c.y;
            hacc[2] = hacc[2]*r + w*h0c.z; hacc[3] = hacc[3]*r + w*h0c.w;
            hacc[4] = hacc[4]*r + w*h1c.x; hacc[5] = hacc[5]*r + w*h1c.y;
            hacc[6] = hacc[6]*r + w*h1c.z; hacc[7] = hacc[7]*r + w*h1c.w;
            tacc[0] = tacc[0]*r + w*a0c.x; tacc[1] = tacc[1]*r + w*a0c.y;
            tacc[2] = tacc[2]*r + w*a0c.z; tacc[3] = tacc[3]*r + w*a0c.w;
            tacc[4] = tacc[4]*r + w*a1c.x; tacc[5] = tacc[5]*r + w*a1c.y;
            tacc[6] = tacc[6]*r + w*a1c.z; tacc[7] = tacc[7]*r + w*a1c.w;
        }
    }
    float inv = 0.125f / (den + 1e-16f);
    float4 o;
    o = {hacc[0]*inv,hacc[1]*inv,hacc[2]*inv,hacc[3]*inv};
    *(float4*)(hagg + (size_t)n*512 + lane*8)     = o;
    o = {hacc[4]*inv,hacc[5]*inv,hacc[6]*inv,hacc[7]*inv};
    *(float4*)(hagg + (size_t)n*512 + lane*8 + 4) = o;
    o = {tacc[0]*inv,tacc[1]*inv,tacc[2]*inv,tacc[3]*inv};
    *(float4*)(tbuf + (size_t)n*512 + lane*8)     = o;
    o = {tacc[4]*inv,tacc[5]*inv,tacc[6]*inv,tacc[7]*inv};
    *(float4*)(tbuf + (size_t)n*512 + lane*8 + 4) = o;
    if (p == 0) sbuf[(size_t)n*8 + h] = den * inv;
}

// Paired partial GEMM, grid (ceil(N/128), 8): R12-exact.
__global__ void __launch_bounds__(256) k_nf_gemm2(
    const float* __restrict__ tbuf, const float* __restrict__ hagg,
    const float* __restrict__ We, const float* __restrict__ Wv,
    float* __restrict__ pbuf, int N)
{
    __shared__ float As[64][132];
    __shared__ __align__(16) float Wt[64][64];
    int tid = threadIdx.x;
    int y = blockIdx.y;
    int n0 = blockIdx.x * 128;
    int wv = tid >> 6, lane = tid & 63;
    int rg = lane >> 3, cg = lane & 7;
    int c0 = cg * 8;
    int rbase = wv * 32 + rg * 4;
    float acc[4][8];
    #pragma unroll
    for (int t = 0; t < 4; ++t)
        #pragma unroll
        for (int i = 0; i < 8; ++i) acc[t][i] = 0.f;
    #pragma unroll
    for (int round = 0; round < 2; ++round) {
        const float* A = round ? hagg : tbuf;
        const float* W = round ? Wv : We;
        if (round) __syncthreads();
        {
            int rt = tid & 127;
            int n = n0 + rt;
            int jh = (tid >> 7) * 32;
            if (n < N) {
                const float* ap = A + (size_t)n*512 + y*64;
                #pragma unroll
                for (int j4 = 0; j4 < 8; ++j4) {
                    int j = jh + j4 * 4;
                    float4 a = *(const float4*)(ap + j);
                    As[j+0][rt] = a.x; As[j+1][rt] = a.y;
                    As[j+2][rt] = a.z; As[j+3][rt] = a.w;
                }
            } else {
                #pragma unroll
                for (int j4 = 0; j4 < 8; ++j4) {
                    int j = jh + j4 * 4;
                    As[j+0][rt] = 0.f; As[j+1][rt] = 0.f;
                    As[j+2][rt] = 0.f; As[j+3][rt] = 0.f;
                }
            }
            #pragma unroll
            for (int i = 0; i < 4; ++i) {
                int idx = tid + i * 256;
                int j = idx >> 4, c4 = (idx & 15) * 4;
                *(float4*)&Wt[j][c4] = *(const float4*)(W + (size_t)j*512 + y*64 + c4);
            }
        }
        __syncthreads();
        #pragma unroll 4
        for (int j = 0; j < 64; ++j) {
            float4 av = *(const float4*)&As[j][rbase];
            float4 w0 = *(const float4*)&Wt[j][c0];
            float4 w1 = *(const float4*)&Wt[j][c0 + 4];
            acc[0][0] += av.x*w0.x; acc[0][1] += av.x*w0.y; acc[0][2] += av.x*w0.z; acc[0][3] += av.x*w0.w;
            acc[0][4] += av.x*w1.x; acc[0][5] += av.x*w1.y; acc[0][6] += av.x*w1.z; acc[0][7] += av.x*w1.w;
            acc[1][0] += av.y*w0.x; acc[1][1] += av.y*w0.y; acc[1][2] += av.y*w0.z; acc[1][3] += av.y*w0.w;
            acc[1][4] += av.y*w1.x; acc[1][5] += av.y*w1.y; acc[1][6] += av.y*w1.z; acc[1][7] += av.y*w1.w;
            acc[2][0] += av.z*w0.x; acc[2][1] += av.z*w0.y; acc[2][2] += av.z*w0.z; acc[2][3] += av.z*w0.w;
            acc[2][4] += av.z*w1.x; acc[2][5] += av.z*w1.y; acc[2][6] += av.z*w1.z; acc[2][7] += av.z*w1.w;
            acc[3][0] += av.w*w0.x; acc[3][1] += av.w*w0.y; acc[3][2] += av.w*w0.z; acc[3][3] += av.w*w0.w;
            acc[3][4] += av.w*w1.x; acc[3][5] += av.w*w1.y; acc[3][6] += av.w*w1.z; acc[3][7] += av.w*w1.w;
        }
    }
    float* out = pbuf + (size_t)y * N * 64;
    #pragma unroll
    for (int t = 0; t < 4; ++t) {
        int n = n0 + rbase + t;
        if (n < N) {
            float4 o0 = {acc[t][0],acc[t][1],acc[t][2],acc[t][3]};
            float4 o1 = {acc[t][4],acc[t][5],acc[t][6],acc[t][7]};
            *(float4*)(out + (size_t)n*64 + c0)     = o0;
            *(float4*)(out + (size_t)n*64 + c0 + 4) = o1;
        }
    }
}

__global__ void __launch_bounds__(256) k_nf_reduce2(
    const float* __restrict__ pbuf, const float* __restrict__ hin,
    const float* __restrict__ sbuf, const float* __restrict__ Ws,
    const float* __restrict__ be, const float* __restrict__ bv,
    const float* __restrict__ bs, float* __restrict__ hnext, int N)
{
    int idx = blockIdx.x * 256 + threadIdx.x;
    int n = idx >> 6, cc = idx & 63;
    if (n >= N) return;
    float a = bs[cc];
    #pragma unroll
    for (int y = 0; y < 8; ++y) a += pbuf[(size_t)y*N*64 + (size_t)n*64 + cc];
    float hv = hin[(size_t)n*64 + cc];
    #pragma unroll 8
    for (int j = 0; j < 64; ++j) a += __shfl(hv, j) * Ws[(size_t)j*64 + cc];
    #pragma unroll
    for (int h = 0; h < 8; ++h)
        a += sbuf[(size_t)n*8 + h] * (be[h*64 + cc] + bv[h*64 + cc]);
    hnext[(size_t)n*64 + cc] = fmaxf(a, 0.f);
}

// hw[n][y*64+cc] = Σ_j h[n][j] euW[y*4096 + j*64 + cc]   grid (ceil(N/128), 2)
__global__ void __launch_bounds__(256) k_eu_pre(
    const float* __restrict__ h, const float* __restrict__ euW,
    float* __restrict__ hw, int N)
{
    __shared__ float As[64][132];
    __shared__ __align__(16) float Wt[64][64];
    int tid = threadIdx.x;
    int y = blockIdx.y;
    int n0 = blockIdx.x * 128;
    {
        int rt = tid & 127;
        int n = n0 + rt;
        int jh = (tid >> 7) * 32;
        if (n < N) {
            const float* ap = h + (size_t)n*64;
            #pragma unroll
            for (int j4 = 0; j4 < 8; ++j4) {
                int j = jh + j4 * 4;
                float4 a = *(const float4*)(ap + j);
                As[j+0][rt] = a.x; As[j+1][rt] = a.y;
                As[j+2][rt] = a.z; As[j+3][rt] = a.w;
            }
        } else {
            #pragma unroll
            for (int j4 = 0; j4 < 8; ++j4) {
                int j = jh + j4 * 4;
                As[j+0][rt] = 0.f; As[j+1][rt] = 0.f;
                As[j+2][rt] = 0.f; As[j+3][rt] = 0.f;
            }
        }
        #pragma unroll
        for (int i = 0; i < 4; ++i) {
            int idx = tid + i * 256;
            *(float4*)&Wt[idx >> 4][(idx & 15) * 4] =
                *(const float4*)(euW + (size_t)y*4096 + idx * 4);
        }
    }
    __syncthreads();
    int wv = tid >> 6, lane = tid & 63;
    int rg = lane >> 3, cg = lane & 7;
    int c0 = cg * 8;
    int rbase = wv * 32 + rg * 4;
    float acc[4][8];
    #pragma unroll
    for (int t = 0; t < 4; ++t)
        #pragma unroll
        for (int i = 0; i < 8; ++i) acc[t][i] = 0.f;
    #pragma unroll 4
    for (int j = 0; j < 64; ++j) {
        float4 av = *(const float4*)&As[j][rbase];
        float4 w0 = *(const float4*)&Wt[j][c0];
        float4 w1 = *(const float4*)&Wt[j][c0 + 4];
        acc[0][0] += av.x*w0.x; acc[0][1] += av.x*w0.y; acc[0][2] += av.x*w0.z; acc[0][3] += av.x*w0.w;
        acc[0][4] += av.x*w1.x; acc[0][5] += av.x*w1.y; acc[0][6] += av.x*w1.z; acc[0][7] += av.x*w1.w;
        acc[1][0] += av.y*w0.x; acc[1][1] += av.y*w0.y; acc[1][2] += av.y*w0.z; acc[1][3] += av.y*w0.w;
        acc[1][4] += av.y*w1.x; acc[1][5] += av.y*w1.y; acc[1][6] += av.y*w1.z; acc[1][7] += av.y*w1.w;
        acc[2][0] += av.z*w0.x; acc[2][1] += av.z*w0.y; acc[2][2] += av.z*w0.z; acc[2][3] += av.z*w0.w;
        acc[2][4] += av.z*w1.x; acc[2][5] += av.z*w1.y; acc[2][6] += av.z*w1.z; acc[2][7] += av.z*w1.w;
        acc[3][0] += av.w*w0.x; acc[3][1] += av.w*w0.y; acc[3][2] += av.w*w0.z; acc[3][3] += av.w*w0.w;
        acc[3][4] += av.w*w1.x; acc[3][5] += av.w*w1.y; acc[3][6] += av.w*w1.z; acc[3][7] += av.w*w1.w;
    }
    #pragma unroll
    for (int t = 0; t < 4; ++t) {
        int n = n0 + rbase + t;
        if (n < N) {
            float4 o0 = {acc[t][0],acc[t][1],acc[t][2],acc[t][3]};
            float4 o1 = {acc[t][4],acc[t][5],acc[t][6],acc[t][7]};
            *(float4*)(hw + (size_t)n*128 + y*64 + c0)     = o0;
            *(float4*)(hw + (size_t)n*128 + y*64 + c0 + 4) = o1;
        }
    }
}

// slot-based: ea2[slot] = relu( hw[src][0:64] + hw[dst][64:128] + ea[slot]@W3 + eub )
__global__ void __launch_bounds__(256) k_edge_update2(
    const float* __restrict__ hw, const float* __restrict__ ea,
    const float* __restrict__ euW2, const float* __restrict__ eub,
    const int2* __restrict__ ipair, const int* __restrict__ idst,
    float* __restrict__ ea2, int E)
{
    __shared__ float As[64][132];
    __shared__ __align__(16) float Wt[64][64];
    __shared__ int sid[128], did[128];
    int tid = threadIdx.x;
    int e0 = blockIdx.x * 128;
    if (tid < 128) {
        int slot = e0 + tid; if (slot >= E) slot = E - 1;
        sid[tid] = ipair[slot].x; did[tid] = idst[slot];
    }
    {
        int et = tid & 127;
        int slot = e0 + et; if (slot >= E) slot = E - 1;
        const float* ap = ea + (size_t)slot * 64;
        int jh = (tid >> 7) * 32;
        #pragma unroll
        for (int j4 = 0; j4 < 8; ++j4) {
            int j = jh + j4 * 4;
            float4 a = *(const float4*)(ap + j);
            As[j+0][et] = a.x; As[j+1][et] = a.y;
            As[j+2][et] = a.z; As[j+3][et] = a.w;
        }
        #pragma unroll
        for (int i = 0; i < 4; ++i) {
            int idx = tid + i * 256;
            *(float4*)&Wt[idx >> 4][(idx & 15) * 4] = *(const float4*)(euW2 + idx * 4);
        }
    }
    __syncthreads();
    int wv = tid >> 6, lane = tid & 63;
    int rg = lane >> 3, cg = lane & 7;
    int c0 = cg * 8;
    int rbase = wv * 32 + rg * 4;
    float acc[4][8];
    float4 b0 = *(const float4*)(eub + c0);
    float4 b1 = *(const float4*)(eub + c0 + 4);
    #pragma unroll
    for (int t = 0; t < 4; ++t) {
        acc[t][0]=b0.x; acc[t][1]=b0.y; acc[t][2]=b0.z; acc[t][3]=b0.w;
        acc[t][4]=b1.x; acc[t][5]=b1.y; acc[t][6]=b1.z; acc[t][7]=b1.w;
    }
    #pragma unroll 4
    for (int j = 0; j < 64; ++j) {
        float4 av = *(const float4*)&As[j][rbase];
        float4 w0 = *(const float4*)&Wt[j][c0];
        float4 w1 = *(const float4*)&Wt[j][c0 + 4];
        acc[0][0] += av.x*w0.x; acc[0][1] += av.x*w0.y; acc[0][2] += av.x*w0.z; acc[0][3] += av.x*w0.w;
        acc[0][4] += av.x*w1.x; acc[0][5] += av.x*w1.y; acc[0][6] += av.x*w1.z; acc[0][7] += av.x*w1.w;
        acc[1][0] += av.y*w0.x; acc[1][1] += av.y*w0.y; acc[1][2] += av.y*w0.z; acc[1][3] += av.y*w0.w;
        acc[1][4] += av.y*w1.x; acc[1][5] += av.y*w1.y; acc[1][6] += av.y*w1.z; acc[1][7] += av.y*w1.w;
        acc[2][0] += av.z*w0.x; acc[2][1] += av.z*w0.y; acc[2][2] += av.z*w0.z; acc[2][3] += av.z*w0.w;
        acc[2][4] += av.z*w1.x; acc[2][5] += av.z*w1.y; acc[2][6] += av.z*w1.z; acc[2][7] += av.z*w1.w;
        acc[3][0] += av.w*w0.x; acc[3][1] += av.w*w0.y; acc[3][2] += av.w*w0.z; acc[3][3] += av.w*w0.w;
        acc[3][4] += av.w*w1.x; acc[3][5] += av.w*w1.y; acc[3][6] += av.w*w1.z; acc[3][7] += av.w*w1.w;
    }
    #pragma unroll
    for (int t = 0; t < 4; ++t) {
        int slot = e0 + rbase + t;
        if (slot < E) {
            int s = sid[rbase + t], d = did[rbase + t];
            const float4* sp = (const float4*)(hw + (size_t)s*128 + c0);
            const float4* dp = (const float4*)(hw + (size_t)d*128 + 64 + c0);
            float4 s0 = sp[0], s1 = sp[1];
            float4 d0 = dp[0], d1 = dp[1];
            float4 o0 = {fmaxf(acc[t][0]+s0.x+d0.x,0.f), fmaxf(acc[t][1]+s0.y+d0.y,0.f),
                         fmaxf(acc[t][2]+s0.z+d0.z,0.f), fmaxf(acc[t][3]+s0.w+d0.w,0.f)};
            float4 o1 = {fmaxf(acc[t][4]+s1.x+d1.x,0.f), fmaxf(acc[t][5]+s1.y+d1.y,0.f),
                         fmaxf(acc[t][6]+s1.z+d1.z,0.f), fmaxf(acc[t][7]+s1.w+d1.w,0.f)};
            *(float4*)(ea2 + (size_t)slot*64 + c0)     = o0;
            *(float4*)(ea2 + (size_t)slot*64 + c0 + 4) = o1;
        }
    }
}

// ---------------- pooling / head ----------------

__global__ void __launch_bounds__(64) k_node_pool(
    const float* __restrict__ h, const int* __restrict__ batch,
    float* __restrict__ npool, float* __restrict__ cn, int N)
{
    int lane = threadIdx.x;
    int n0 = blockIdx.x * 64;
    float acc = 0.f; int cur = -1; int run = 0;
    for (int i = 0; i < 64; ++i) {
        int n = n0 + i;
        if (n >= N) break;
        int b = batch[n];
        if (b != cur) {
            if (cur >= 0) {
                atomicAdd(npool + (size_t)cur*64 + lane, acc);
                if (lane == 0) atomicAdd(cn + cur, (float)run);
            }
            cur = b; acc = 0.f; run = 0;
        }
        acc += h[(size_t)n*64 + lane];
        ++run;
    }
    if (cur >= 0) {
        atomicAdd(npool + (size_t)cur*64 + lane, acc);
        if (lane == 0) atomicAdd(cn + cur, (float)run);
    }
}

// slot-ordered: batch id per slot via iebs
__global__ void __launch_bounds__(256) k_edge_pool2(
    const float* __restrict__ ea, const int* __restrict__ iebs,
    float* __restrict__ rep, int E)
{
    __shared__ float pool_s[32][64];
    __shared__ float cnt_s[32];
    int tid = threadIdx.x;
    for (int i = tid; i < 2048; i += 256) ((float*)pool_s)[i] = 0.f;
    if (tid < 32) cnt_s[tid] = 0.f;
    __syncthreads();
    int wv = tid >> 6, lane = tid & 63;
    int base = blockIdx.x * 64 + wv * 16;
    int b16[16]; float v16[16];
    #pragma unroll
    for (int u = 0; u < 16; ++u) {
        int slot = base + u;
        bool ok = (slot < E);
        b16[u] = ok ? iebs[slot] : -1;
        v16[u] = ok ? ea[(size_t)slot*64 + lane] : 0.f;
    }
    #pragma unroll
    for (int u = 0; u < 16; ++u) {
        if (b16[u] >= 0) {
            atomicAdd(&pool_s[b16[u]][lane], v16[u]);
            if (lane == 0) atomicAdd(&cnt_s[b16[u]], 1.f);
        }
    }
    __syncthreads();
    float* myrep = rep + (size_t)(blockIdx.x & 7) * 2080;
    for (int i = tid; i < 2048; i += 256) atomicAdd(myrep + i, ((float*)pool_s)[i]);
    if (tid < 32) atomicAdd(myrep + 2048 + tid, cnt_s[tid]);
}

__global__ void __launch_bounds__(256) k_pool_merge(
    const float* __restrict__ rep, float* __restrict__ epool, float* __restrict__ ce)
{
    int i = blockIdx.x * 256 + threadIdx.x;
    if (i < 2080) {
        float s = 0.f;
        #pragma unroll
        for (int r = 0; r < 8; ++r) s += rep[(size_t)r*2080 + i];
        if (i < 2048) epool[i] = s; else ce[i - 2048] = s;
    }
}

__global__ void __launch_bounds__(64) k_head_mlp(
    const float* __restrict__ npool, const float* __restrict__ epool,
    const float* __restrict__ cn, const float* __restrict__ ce,
    const float* __restrict__ rW1, const float* __restrict__ rb1,
    const float* __restrict__ rW2, const float* __restrict__ rb2,
    const float* __restrict__ rW3, const float* __restrict__ rb3,
    float* __restrict__ out)
{
    __shared__ float g[128];
    __shared__ float h1[64];
    __shared__ float h2[64];
    int b = blockIdx.x, lane = threadIdx.x;
    float cnv = fmaxf(cn[b], 1.f), cev = fmaxf(ce[b], 1.f);
    g[lane]      = npool[(size_t)b*64 + lane] / cnv;
    g[64 + lane] = epool[(size_t)b*64 + lane] / cev;
    __syncthreads();
    float acc = rb1[lane];
    #pragma unroll 4
    for (int j = 0; j < 128; ++j) acc += g[j] * rW1[j*64 + lane];
    h1[lane] = fmaxf(acc, 0.f);
    __syncthreads();
    acc = rb2[lane];
    #pragma unroll 4
    for (int j = 0; j < 64; ++j) acc += h1[j] * rW2[j*64 + lane];
    h2[lane] = fmaxf(acc, 0.f);
    __syncthreads();
    if (lane < 2) {
        float o = rb3[lane];
        for (int j = 0; j < 64; ++j) o += h2[j] * rW3[j*2 + lane];
        out[b*2 + lane] = tanhf(o);
    }
}

// ---------------- launcher ----------------

extern "C" void kernel_launch(void* const* d_in, const int* in_sizes, int n_in,
                              void* d_out, int out_size, void* d_ws, size_t ws_size,
                              hipStream_t stream)
{
    const float* x         = (const float*)d_in[0];
    const float* edge_attr = (const float*)d_in[1];
    const float* means     = (const float*)d_in[2];
    const float* log_stds  = (const float*)d_in[3];
    const float* spW       = (const float*)d_in[4];
    const float* spb       = (const float*)d_in[5];
    const float* neW       = (const float*)d_in[6];
    const float* neb       = (const float*)d_in[7];
    const float* eeW       = (const float*)d_in[8];
    const float* eeb       = (const float*)d_in[9];
    const float* Wq        = (const float*)d_in[10];
    const float* bq        = (const float*)d_in[11];
    const float* Wk        = (const float*)d_in[12];
    const float* bk        = (const float*)d_in[13];
    const float* Wv        = (const float*)d_in[14];
    const float* bv        = (const float*)d_in[15];
    const float* We        = (const float*)d_in[16];
    const float* be        = (const float*)d_in[17];
    const float* Ws        = (const float*)d_in[18];
    const float* bs        = (const float*)d_in[19];
    const float* euW       = (const float*)d_in[20];
    const float* eub       = (const float*)d_in[21];
    const float* rW1       = (const float*)d_in[22];
    const float* rb1       = (const float*)d_in[23];
    const float* rW2       = (const float*)d_in[24];
    const float* rb2       = (const float*)d_in[25];
    const float* rW3       = (const float*)d_in[26];
    const float* rb3       = (const float*)d_in[27];
    const int* eidx        = (const int*)d_in[28];
    const int* batch       = (const int*)d_in[29];

    int N = in_sizes[0] / 7;
    int E = in_sizes[1] / 4;
    const int G = 32;
    const int* srcp = eidx;
    const int* dstp = eidx + E;

    float* ws = (float*)d_ws;
    size_t fl = 0;
    float* hA    = ws + fl; fl += (size_t)N * 64;
    float* hB    = ws + fl; fl += (size_t)N * 64;
    float* eaA   = ws + fl; fl += (size_t)E * 64;   // slot-ordered
    float* eaB   = ws + fl; fl += (size_t)E * 64;   // slot-ordered
    float* B1    = ws + fl; fl += (size_t)N * 512;  // qk -> hagg
    float* B2    = ws + fl; fl += (size_t)N * 512;  // qe2 -> tbuf
    float* B3    = ws + fl; fl += (size_t)N * 512;  // pbuf (8 x N64), then hw (N x 128)
    float* alpha = ws + fl; fl += (size_t)E * 8;    // wbuf (E*4, slot-indexed) at init only
    float* sbuf  = ws + fl; fl += (size_t)N * 8;
    float* npool = ws + fl; fl += (size_t)G * 64;
    float* epool = ws + fl; fl += (size_t)G * 64;
    float* cn    = ws + fl; fl += G;
    float* ce    = ws + fl; fl += G;
    float* Mk3   = ws + fl; fl += 3 * 64 * 512;
    float* Me3   = ws + fl; fl += 3 * 64 * 512;
    float* bqk3  = ws + fl; fl += 3 * 512;
    float* bqe3  = ws + fl; fl += 3 * 512;
    float* wqb3  = ws + fl; fl += 3 * 512;
    float* cb3   = ws + fl; fl += 24;
    float* rep   = ws + fl; fl += 8 * 2080;
    int* ideg  = (int*)(ws + fl); fl += (size_t)N;
    int* ihead = (int*)(ws + fl); fl += (size_t)N;
    int2* ipair = (int2*)(ws + fl); fl += (size_t)E * 2;   // 8B-aligned (even offset)
    int* idst  = (int*)(ws + fl); fl += (size_t)E;
    int* iebs  = (int*)(ws + fl); fl += (size_t)E;
    int* iptr  = (int*)(ws + fl); fl += (size_t)N + 1;
    // ~48.0M floats = 191.9 MB (ws known >= ~194 MB)

    float* wbuf = alpha;

    hipMemsetAsync(npool, 0, (size_t)(G * 130) * sizeof(float), stream);
    hipMemsetAsync(rep, 0, (size_t)(8 * 2080) * sizeof(float), stream);
    hipMemsetAsync(ideg, 0, (size_t)N * sizeof(int), stream);

    k_node_embed<<<(N * 64 + 255) / 256, 256, 0, stream>>>(x, neW, neb, hA, N);
    k_hist<<<(E + 255) / 256, 256, 0, stream>>>(dstp, ideg, E);
    k_scan<<<1, 1024, 0, stream>>>(ideg, iptr, ihead, N);
    k_scatter<<<(E + 255) / 256, 256, 0, stream>>>(dstp, srcp, batch, ihead,
                                                   ipair, idst, iebs, E);
    k_edge_w<<<(E + 255) / 256, 256, 0, stream>>>(x, means, log_stds, ipair, idst, wbuf, E);
    k_edge_ea<<<((size_t)E * 64 + 255) / 256, 256, 0, stream>>>(edge_attr, wbuf, ipair,
                                                                spW, spb, eeW, eeb, eaA, E);
    k_wprod_all<<<dim3(8, 2, 3), 256, 0, stream>>>(Wq, bq, Wk, We, Mk3, Me3, bqk3, bqe3);
    k_wqb_all<<<3, 64, 0, stream>>>(Wq, bq, bk, be, wqb3, cb3);

    float* hcur = hA;  float* hnext = hB;
    float* eacur = eaA; float* eanext = eaB;
    for (int l = 0; l < 3; ++l) {
        const float* Wv_l = Wv + (size_t)l * 64 * 512;
        const float* We_l = We + (size_t)l * 64 * 512;
        const float* bv_l = bv + (size_t)l * 512;
        const float* be_l = be + (size_t)l * 512;
        const float* euW_l = euW + (size_t)l * 192 * 64;

        k_proj16<<<dim3((N + 127) / 128, 16), 256, 0, stream>>>(
            hcur,
            Mk3 + (size_t)l * 32768, bqk3 + (size_t)l * 512, B1,
            Me3 + (size_t)l * 32768, bqe3 + (size_t)l * 512, B2, N);

        k_attn_fused<<<(N + 3) / 4, 256, 0, stream>>>(B1, B2,
                                                      wqb3 + (size_t)l * 512,
                                                      cb3 + (size_t)l * 8,
                                                      eacur, hcur,
                                                      iptr, ipair,
                                                      B1 /*hagg*/, B2 /*tbuf*/, sbuf, N);
        k_nf_gemm2<<<dim3((N + 127) / 128, 8), 256, 0, stream>>>(B2, B1, We_l, Wv_l, B3, N);
        k_nf_reduce2<<<((size_t)N * 64 + 255) / 256, 256, 0, stream>>>(B3, hcur, sbuf,
                                                                       Ws + (size_t)l * 64 * 64,
                                                                       be_l, bv_l,
                                                                       bs + (size_t)l * 64,
                                                                       hnext, N);
        k_eu_pre<<<dim3((N + 127) / 128, 2), 256, 0, stream>>>(hnext, euW_l, B3, N);
        k_edge_update2<<<(E + 127) / 128, 256, 0, stream>>>(B3, eacur, euW_l + 2 * 4096,
                                                            eub + (size_t)l * 64,
                                                            ipair, idst, eanext, E);
        float* t1 = hcur; hcur = hnext; hnext = t1;
        float* t2 = eacur; eacur = eanext; eanext = t2;
    }

    k_node_pool<<<(N + 63) / 64, 64, 0, stream>>>(hcur, batch, npool, cn, N);
    k_edge_pool2<<<(E + 63) / 64, 256, 0, stream>>>(eacur, iebs, rep, E);
    k_pool_merge<<<9, 256, 0, stream>>>(rep, epool, ce);
    k_head_mlp<<<G, 64, 0, stream>>>(npool, epool, cn, ce, rW1, rb1, rW2, rb2, rW3, rb3,
                                     (float*)d_out);
}